// Round 5
// baseline (1108.382 us; speedup 1.0000x reference)
//
#include <hip/hip_runtime.h>
#include <math.h>

#define B_ 8
#define T_ 1000
#define F_ 96
#define C_ 16
#define D_ 64
#define EPS_ 1e-5f

__device__ __forceinline__ float gelu_erf(float v){
    return 0.5f*v*(1.0f+erff(v*0.70710678118654752440f));
}
__device__ __forceinline__ float dot4(float4 a, float4 b){
    return a.x*b.x + a.y*b.y + a.z*b.z + a.w*b.w;
}
__device__ __forceinline__ float fast_sigmoid(float a){
    return __builtin_amdgcn_rcpf(1.f + __expf(-a));
}
__device__ __forceinline__ float fast_tanh(float a){
    return 1.f - 2.f*__builtin_amdgcn_rcpf(1.f + __expf(2.f*a));
}
// precise LDS-only fence: orders DS ops without draining vmcnt (prefetch stays in flight)
__device__ __forceinline__ void ds_fence(){
    asm volatile("s_waitcnt lgkmcnt(0)" ::: "memory");
}
// wave-synchronous LDS fence for k_tail (not on a global-prefetch critical path there)
__device__ __forceinline__ void wsync(){
    __builtin_amdgcn_wave_barrier();
    asm volatile("s_waitcnt lgkmcnt(0)" ::: "memory");
    __builtin_amdgcn_wave_barrier();
}

// ---------------- Kernel A: conv_in -> x [B,T,F,C] ----------------
__global__ __launch_bounds__(128) void k_conv_in(
    const float* __restrict__ in, const float* __restrict__ g, const float* __restrict__ bb,
    const float* __restrict__ w_in, const float* __restrict__ b_in,
    float* __restrict__ x)
{
    int bt = blockIdx.x; int b = bt / T_; int t = bt % T_;
    int tid = threadIdx.x;
    __shared__ float r0[128], r1[128], r2[128], r3[128];
    float i0=0.f, i1=0.f;
    size_t base0 = ((size_t)(b*2+0)*T_ + t)*F_;
    size_t base1 = ((size_t)(b*2+1)*T_ + t)*F_;
    if (tid < F_){ i0 = in[base0+tid]; i1 = in[base1+tid]; }
    r0[tid]=i0; r1[tid]=i0*i0; r2[tid]=i1; r3[tid]=i1*i1;
    __syncthreads();
    for (int s=64; s>0; s>>=1){
        if (tid < s){ r0[tid]+=r0[tid+s]; r1[tid]+=r1[tid+s]; r2[tid]+=r2[tid+s]; r3[tid]+=r3[tid+s]; }
        __syncthreads();
    }
    float m0 = r0[0]*(1.f/F_), m1 = r2[0]*(1.f/F_);
    float ri0 = rsqrtf(r1[0]*(1.f/F_) - m0*m0 + EPS_);
    float ri1 = rsqrtf(r3[0]*(1.f/F_) - m1*m1 + EPS_);
    if (tid < F_){
        float gg = g[tid], b0 = bb[tid];
        float y0 = (i0-m0)*ri0*gg + b0;
        float y1 = (i1-m1)*ri1*gg + b0;
        float xv[16];
        #pragma unroll
        for (int c=0;c<C_;++c){
            xv[c] = gelu_erf(w_in[c*2+0]*y0 + w_in[c*2+1]*y1 + b_in[c]);
        }
        float4* xp = (float4*)(x + (((size_t)b*T_+t)*F_ + tid)*C_);
        xp[0] = make_float4(xv[0],xv[1],xv[2],xv[3]);
        xp[1] = make_float4(xv[4],xv[5],xv[6],xv[7]);
        xp[2] = make_float4(xv[8],xv[9],xv[10],xv[11]);
        xp[3] = make_float4(xv[12],xv[13],xv[14],xv[15]);
    }
}

// ---------------- Kernel B: ConvGRU — 4 chains/wave, h replicated per lane ----------------
// 192 blocks x 64 threads. lane = ch*16 + c; chain = (b, f0+ch).
// Per step: full gate dots in-register; ONE LDS round (lgkm-only fence) redistributes h.
__global__ __launch_bounds__(64) void k_gru(
    const float* __restrict__ x, const float* __restrict__ wx, const float* __restrict__ wh,
    float* __restrict__ hs, float* __restrict__ d_out)
{
    int blk = blockIdx.x;
    int b = blk / 24, f0 = (blk % 24) * 4;
    int lane = threadIdx.x;
    int c = lane & 15, ch = lane >> 4;
    int f = f0 + ch;

    __shared__ float hsh[64];

    float4 Wxz[4], Wxr[4], Wxn[4], Whz[4], Whr[4], Whn[4];
    #pragma unroll
    for (int q=0;q<4;++q){
        Wxz[q] = *(const float4*)(wx + ( 0+c)*16 + 4*q);
        Wxr[q] = *(const float4*)(wx + (16+c)*16 + 4*q);
        Wxn[q] = *(const float4*)(wx + (32+c)*16 + 4*q);
        Whz[q] = *(const float4*)(wh + ( 0+c)*16 + 4*q);
        Whr[q] = *(const float4*)(wh + (16+c)*16 + 4*q);
        Whn[q] = *(const float4*)(wh + (32+c)*16 + 4*q);
    }

    const float4* xp = (const float4*)(x + ((size_t)b*T_)*(F_*C_) + f*C_);  // +t*384
    float4 cur[4], nx1[4], nx2[4];
    #pragma unroll
    for (int q=0;q<4;++q){ cur[q]=xp[q]; nx1[q]=xp[384+q]; nx2[q]=xp[768+q]; }

    float4 h4[4];
    #pragma unroll
    for (int q=0;q<4;++q) h4[q] = make_float4(0.f,0.f,0.f,0.f);
    float hc = 0.f;

    const float* hrow = hsh + ch*16;
    size_t hsb = (size_t)b*T_*(F_*C_) + f0*C_ + lane;   // += 1536 per t (coalesced 256B/wave)

    for (int t=0; t<T_; ++t){
        float4 ld[4];
        if (t+3 < T_){
            #pragma unroll
            for (int q=0;q<4;++q) ld[q] = xp[(size_t)(t+3)*384 + q];
        }
        float zx = dot4(Wxz[0],cur[0])+dot4(Wxz[1],cur[1])+dot4(Wxz[2],cur[2])+dot4(Wxz[3],cur[3]);
        float rx = dot4(Wxr[0],cur[0])+dot4(Wxr[1],cur[1])+dot4(Wxr[2],cur[2])+dot4(Wxr[3],cur[3]);
        float nxv= dot4(Wxn[0],cur[0])+dot4(Wxn[1],cur[1])+dot4(Wxn[2],cur[2])+dot4(Wxn[3],cur[3]);
        float zh = dot4(Whz[0],h4[0])+dot4(Whz[1],h4[1])+dot4(Whz[2],h4[2])+dot4(Whz[3],h4[3]);
        float rh = dot4(Whr[0],h4[0])+dot4(Whr[1],h4[1])+dot4(Whr[2],h4[2])+dot4(Whr[3],h4[3]);
        float nh = dot4(Whn[0],h4[0])+dot4(Whn[1],h4[1])+dot4(Whn[2],h4[2])+dot4(Whn[3],h4[3]);
        float z = fast_sigmoid(zx+zh);
        float r = fast_sigmoid(rx+rh);
        float n = fast_tanh(nxv + r*nh);
        float hn = n + z*(hc - n);
        hc = hn;
        hsh[lane] = hn;                      // ds_write (on critical path)
        hs[hsb + (size_t)t*(F_*C_)] = hn;    // global store (off critical path, no vmcnt wait)
        ds_fence();                          // lgkmcnt(0) ONLY — prefetch loads stay in flight
        #pragma unroll
        for (int q=0;q<4;++q) h4[q] = *(const float4*)(hrow + 4*q);  // broadcast reads
        #pragma unroll
        for (int q=0;q<4;++q){ cur[q]=nx1[q]; nx1[q]=nx2[q]; nx2[q]=ld[q]; }
    }
    d_out[(size_t)B_*2*T_*F_ + ((size_t)b*C_ + c)*F_ + f] = hc;
}

// ---------------- Kernel C: fused attention + MLP + conv_out ----------------
// LDS map (floats). All float4-read bases 16B aligned; strides chosen for <=2-way banks.
#define OX2   0        // x2/y/x3 [96][16]  f*16+c            1536
#define OYM   1536     // ymean [24][16]  m*16+c               384
#define OKL   1920     // k_long [24][68]                     1632
#define OVL   3552     // v_long [24][68]                     1632
#define OWQ   5184     // wq as float4 tiles: f4idx=c4*64+d   1024
#define OWK   6208
#define OWV   7232
#define OWO   8256     // wo as float4 tiles: f4idx=dd4*16+cc 1024
#define OWM1  9280     // [16][16]                             256
#define OWM2  9536     //                                      256
#define OMEA  9792     // 16
#define ORST  9808     // 16
#define OSC   9824     // LN partial scratch 512
#define OWS   10336    // per-wave scratch x4, stride 672: K[4*68] Q[4*68] A[112+pad]
#define WSSTR 672
#define TOTF  (OWS + 4*WSSTR)   // 13024 floats = 52096 B

__device__ __forceinline__ void ln_stats16(float* S, int tid){
    int c = tid & 15, g = tid >> 4;
    float s=0.f, q=0.f;
    #pragma unroll
    for (int i=0;i<6;++i){
        float v = S[OX2 + (g*6+i)*16 + c];
        s += v; q += v*v;
    }
    S[OSC + g*16 + c] = s;
    S[OSC + 256 + g*16 + c] = q;
    __syncthreads();
    if (tid < 16){
        float Sm=0.f, Q=0.f;
        #pragma unroll
        for (int g2=0; g2<16; ++g2){
            Sm += S[OSC + g2*16 + tid];
            Q  += S[OSC + 256 + g2*16 + tid];
        }
        float m = Sm*(1.f/96.f);
        S[OMEA+tid] = m;
        S[ORST+tid] = rsqrtf(Q*(1.f/96.f) - m*m + EPS_);
    }
    __syncthreads();
}

__global__ __launch_bounds__(256) void k_tail(
    const float* __restrict__ x, const float* __restrict__ hs, const float* __restrict__ input,
    const float* __restrict__ ln_att_g, const float* __restrict__ ln_att_b,
    const float* __restrict__ wq, const float* __restrict__ bq,
    const float* __restrict__ wk, const float* __restrict__ bk,
    const float* __restrict__ wv, const float* __restrict__ bv,
    const float* __restrict__ wo, const float* __restrict__ bo,
    const float* __restrict__ ln_m_g, const float* __restrict__ ln_m_b,
    const float* __restrict__ wm1, const float* __restrict__ bm1,
    const float* __restrict__ wm2, const float* __restrict__ bm2,
    const float* __restrict__ ln_o_g, const float* __restrict__ ln_o_b,
    const float* __restrict__ w_out, const float* __restrict__ b_out,
    float* __restrict__ out)
{
    int bt = blockIdx.x; int b = bt / T_; int t = bt % T_;
    int tid = threadIdx.x;
    int w = tid >> 6, lane = tid & 63;
    __shared__ float S[TOTF];
    float4* X2f4 = (float4*)(S + OX2);
    float4* YM4  = (float4*)(S + OYM);
    const float4* WQ4 = (const float4*)(S + OWQ);
    const float4* WK4 = (const float4*)(S + OWK);
    const float4* WV4 = (const float4*)(S + OWV);
    const float4* WO4 = (const float4*)(S + OWO);

    size_t xbase = ((size_t)b*T_ + t)*(size_t)(F_*C_);

    // lane-resident biases (lane = d for qkv phases; lane&15 = c for out-proj)
    float bq_r = bq[lane], bk_r = bk[lane], bv_r = bv[lane];
    float bo_r = bo[lane & 15];

    // P0: x2 = x + hs (float4 coalesced); stage weights as float4 tiles
    {
        const float4* xg = (const float4*)(x + xbase);
        const float4* hg = (const float4*)(hs + xbase);
        for (int i4 = tid; i4 < 384; i4 += 256){
            float4 a = xg[i4], h = hg[i4];
            X2f4[i4] = make_float4(a.x+h.x, a.y+h.y, a.z+h.z, a.w+h.w);
        }
        // wq/wk/wv global [64][16]: tid -> d=tid>>2, c4=tid&3 ; store f4idx c4*64+d
        {
            int d = tid >> 2, c4 = tid & 3;
            ((float4*)(S+OWQ))[c4*64 + d] = ((const float4*)wq)[tid];
            ((float4*)(S+OWK))[c4*64 + d] = ((const float4*)wk)[tid];
            ((float4*)(S+OWV))[c4*64 + d] = ((const float4*)wv)[tid];
        }
        // wo global [16][64]: tid -> c=tid>>4, dd4=tid&15 ; store f4idx dd4*16+c
        {
            int c2 = tid >> 4, dd4 = tid & 15;
            ((float4*)(S+OWO))[dd4*16 + c2] = ((const float4*)wo)[tid];
        }
        S[OWM1 + tid] = wm1[tid];
        S[OWM2 + tid] = wm2[tid];
    }
    __syncthreads();

    // P1/P2: attention LN
    ln_stats16(S, tid);
    for (int i4 = tid; i4 < 384; i4 += 256){
        int f = i4 >> 2, c4 = i4 & 3;
        float4 v = X2f4[i4];
        float4 m4 = *(float4*)(S + OMEA + 4*c4);
        float4 r4 = *(float4*)(S + ORST + 4*c4);
        float gg = ln_att_g[f], b2 = ln_att_b[f];
        v.x = (v.x - m4.x)*r4.x*gg + b2;
        v.y = (v.y - m4.y)*r4.y*gg + b2;
        v.z = (v.z - m4.z)*r4.z*gg + b2;
        v.w = (v.w - m4.w)*r4.w*gg + b2;
        X2f4[i4] = v;
    }
    __syncthreads();

    // P3: segment means
    for (int i4 = tid; i4 < 96; i4 += 256){
        int m = i4 >> 2, c4 = i4 & 3;
        float4 a0 = X2f4[(4*m+0)*4 + c4];
        float4 a1 = X2f4[(4*m+1)*4 + c4];
        float4 a2 = X2f4[(4*m+2)*4 + c4];
        float4 a3 = X2f4[(4*m+3)*4 + c4];
        YM4[m*4 + c4] = make_float4(0.25f*(a0.x+a1.x+a2.x+a3.x), 0.25f*(a0.y+a1.y+a2.y+a3.y),
                                    0.25f*(a0.z+a1.z+a2.z+a3.z), 0.25f*(a0.w+a1.w+a2.w+a3.w));
    }
    __syncthreads();

    // P4: k_long/v_long — wave w computes m = 6w..6w+5, lane = d
    {
        int m0 = 6*w;
        float ak[6], av[6];
        #pragma unroll
        for (int j=0;j<6;++j){ ak[j] = bk_r; av[j] = bv_r; }
        #pragma unroll
        for (int c4=0;c4<4;++c4){
            float4 k4 = WK4[c4*64 + lane];
            float4 v4 = WV4[c4*64 + lane];
            #pragma unroll
            for (int j=0;j<6;++j){
                float4 y4 = YM4[(m0+j)*4 + c4];     // broadcast
                ak[j] += dot4(k4, y4);
                av[j] += dot4(v4, y4);
            }
        }
        #pragma unroll
        for (int j=0;j<6;++j){
            S[OKL + (m0+j)*68 + lane] = ak[j];
            S[OVL + (m0+j)*68 + lane] = av[j];
        }
    }
    __syncthreads();

    // P5: attention — wave w owns segments 6w..6w+5; wave-synchronous
    float* wsK = S + OWS + w*WSSTR;
    float* wsQ = wsK + 272;
    float* wsA = wsK + 544;                 // transposed: a[key j][r]
    float4* wsA4 = (float4*)wsA;
    for (int si=0; si<6; ++si){
        int s = 6*w + si;
        // qkv for the 4 rows of this segment (lane = d)
        float aq[4], ak2[4], av2[4];
        #pragma unroll
        for (int r=0;r<4;++r){ aq[r]=bq_r; ak2[r]=bk_r; av2[r]=bv_r; }
        #pragma unroll
        for (int c4=0;c4<4;++c4){
            float4 q4 = WQ4[c4*64 + lane];
            float4 k4 = WK4[c4*64 + lane];
            float4 v4 = WV4[c4*64 + lane];
            #pragma unroll
            for (int r=0;r<4;++r){
                float4 y4 = X2f4[(4*s+r)*4 + c4];    // broadcast
                aq[r] += dot4(q4, y4);
                ak2[r] += dot4(k4, y4);
                av2[r] += dot4(v4, y4);
            }
        }
        #pragma unroll
        for (int r=0;r<4;++r){
            wsQ[r*68 + lane] = aq[r];
            wsK[r*68 + lane] = ak2[r];
        }
        wsync();
        // scores + softmax: lane = (r2 = lane>>4, jj = lane&15); keys jj (4 loc + 12 long) and jj+16
        {
            int r2 = lane >> 4, jj = lane & 15;
            const float* qrow = wsQ + r2*68;
            const float* k1 = (jj < 4) ? (wsK + jj*68) : (S + OKL + (jj-4)*68);
            const float* k2p = S + OKL + (jj+12)*68;   // valid only jj<12 (guarded below)
            float a1 = 0.f, a2 = 0.f;
            #pragma unroll
            for (int dd4=0; dd4<16; ++dd4){
                float4 q4  = *(const float4*)(qrow + 4*dd4);
                float4 k14 = *(const float4*)(k1   + 4*dd4);
                float4 k24 = *(const float4*)(k2p  + 4*dd4);
                a1 += dot4(q4, k14);
                a2 += dot4(q4, k24);
            }
            float s1 = a1*0.125f;
            float s2 = (jj < 12) ? a2*0.125f : -INFINITY;
            float mx = fmaxf(s1, s2);
            #pragma unroll
            for (int off=8; off; off>>=1) mx = fmaxf(mx, __shfl_xor(mx, off, 16));
            float p1 = expf(s1 - mx);
            float p2 = (jj < 12) ? expf(s2 - mx) : 0.f;
            float sm = p1 + p2;
            #pragma unroll
            for (int off=8; off; off>>=1) sm += __shfl_xor(sm, off, 16);
            float inv = 1.f/sm;
            wsA[jj*4 + r2] = p1*inv;
            if (jj < 12) wsA[(16+jj)*4 + r2] = p2*inv;
        }
        wsync();
        // o = a_loc·v_loc + a_long·v_long  (lane = d); overwrite wsK rows with o
        {
            float o0, o1, o2, o3;
            float4 aj = wsA4[0];
            o0 = aj.x*av2[0]; o1 = aj.y*av2[0]; o2 = aj.z*av2[0]; o3 = aj.w*av2[0];
            #pragma unroll
            for (int j=1;j<4;++j){
                aj = wsA4[j];
                o0 += aj.x*av2[j]; o1 += aj.y*av2[j]; o2 += aj.z*av2[j]; o3 += aj.w*av2[j];
            }
            #pragma unroll
            for (int m=0;m<24;++m){
                float vm = S[OVL + m*68 + lane];
                float4 am = wsA4[4+m];              // broadcast
                o0 += am.x*vm; o1 += am.y*vm; o2 += am.z*vm; o3 += am.w*vm;
            }
            wsync();                                 // everyone done reading wsK (scores)
            wsK[0*68 + lane] = o0;
            wsK[1*68 + lane] = o1;
            wsK[2*68 + lane] = o2;
            wsK[3*68 + lane] = o3;
        }
        wsync();
        // out-proj + residual -> x3 written into X2 (rows owned by this wave)
        {
            int r2 = lane >> 4, cc = lane & 15;
            const float* orow = wsK + r2*68;
            float acc = bo_r;
            #pragma unroll
            for (int dd4=0; dd4<16; ++dd4){
                float4 w4 = WO4[dd4*16 + cc];
                float4 o4 = *(const float4*)(orow + 4*dd4);  // broadcast per r-group
                acc += dot4(w4, o4);
            }
            int fc = 4*s + r2;
            float resid = x[xbase + fc*16 + cc] + hs[xbase + fc*16 + cc];
            S[OX2 + fc*16 + cc] = resid + acc;
        }
        wsync();
    }
    __syncthreads();

    // P6: MLP
    ln_stats16(S, tid);
    for (int i4 = tid; i4 < 384; i4 += 256){
        int f = i4 >> 2, c4 = i4 & 3;
        float4 v = X2f4[i4];
        float4 m4 = *(float4*)(S + OMEA + 4*c4);
        float4 r4 = *(float4*)(S + ORST + 4*c4);
        float gg = ln_m_g[f], b2 = ln_m_b[f];
        v.x = (v.x - m4.x)*r4.x*gg + b2;
        v.y = (v.y - m4.y)*r4.y*gg + b2;
        v.z = (v.z - m4.z)*r4.z*gg + b2;
        v.w = (v.w - m4.w)*r4.w*gg + b2;
        ((float4*)(S+OKL))[i4] = v;                   // ynorm in KL region
    }
    __syncthreads();
    for (int i4 = tid; i4 < 384; i4 += 256){
        int f = i4 >> 2, cb = i4 & 3;
        float4 acc = *(const float4*)(bm1 + 4*cb);
        #pragma unroll
        for (int c4=0;c4<4;++c4){
            float4 yn4 = ((float4*)(S+OKL))[f*4 + c4];
            float4 w0 = *(float4*)(S + OWM1 + (4*cb+0)*16 + 4*c4);
            float4 w1 = *(float4*)(S + OWM1 + (4*cb+1)*16 + 4*c4);
            float4 w2 = *(float4*)(S + OWM1 + (4*cb+2)*16 + 4*c4);
            float4 w3 = *(float4*)(S + OWM1 + (4*cb+3)*16 + 4*c4);
            acc.x += dot4(w0, yn4); acc.y += dot4(w1, yn4);
            acc.z += dot4(w2, yn4); acc.w += dot4(w3, yn4);
        }
        acc.x = gelu_erf(acc.x); acc.y = gelu_erf(acc.y);
        acc.z = gelu_erf(acc.z); acc.w = gelu_erf(acc.w);
        ((float4*)(S+OVL))[i4] = acc;                 // y1 in VL region
    }
    __syncthreads();
    for (int i4 = tid; i4 < 384; i4 += 256){
        int f = i4 >> 2, cb = i4 & 3;
        float4 acc = *(const float4*)(bm2 + 4*cb);
        #pragma unroll
        for (int c4=0;c4<4;++c4){
            float4 y14 = ((float4*)(S+OVL))[f*4 + c4];
            float4 w0 = *(float4*)(S + OWM2 + (4*cb+0)*16 + 4*c4);
            float4 w1 = *(float4*)(S + OWM2 + (4*cb+1)*16 + 4*c4);
            float4 w2 = *(float4*)(S + OWM2 + (4*cb+2)*16 + 4*c4);
            float4 w3 = *(float4*)(S + OWM2 + (4*cb+3)*16 + 4*c4);
            acc.x += dot4(w0, y14); acc.y += dot4(w1, y14);
            acc.z += dot4(w2, y14); acc.w += dot4(w3, y14);
        }
        float4 xv = X2f4[i4];
        X2f4[i4] = make_float4(xv.x+acc.x, xv.y+acc.y, xv.z+acc.z, xv.w+acc.w);
    }
    __syncthreads();

    // P7: conv_out + outer residual
    ln_stats16(S, tid);
    if (tid < 192){
        int ch = tid >= 96, f = tid - 96*ch;
        float gg = ln_o_g[f], b2 = ln_o_b[f];
        float acc = b_out[ch];
        #pragma unroll
        for (int c4=0;c4<4;++c4){
            float4 x4 = X2f4[f*4 + c4];
            float4 m4 = *(float4*)(S + OMEA + 4*c4);
            float4 r4 = *(float4*)(S + ORST + 4*c4);
            float4 w4 = *(const float4*)(w_out + ch*16 + 4*c4);
            float4 tm;
            tm.x = (x4.x - m4.x)*r4.x*gg + b2;
            tm.y = (x4.y - m4.y)*r4.y*gg + b2;
            tm.z = (x4.z - m4.z)*r4.z*gg + b2;
            tm.w = (x4.w - m4.w)*r4.w*gg + b2;
            acc += dot4(w4, tm);
        }
        size_t oidx = ((size_t)(b*2+ch)*T_ + t)*F_ + f;
        out[oidx] = input[oidx] + tanhf(acc);
    }
}

extern "C" void kernel_launch(void* const* d_in, const int* in_sizes, int n_in,
                              void* d_out, int out_size, void* d_ws, size_t ws_size,
                              hipStream_t stream)
{
    const float* input   = (const float*)d_in[0];
    const float* ln_in_g = (const float*)d_in[1];
    const float* ln_in_b = (const float*)d_in[2];
    const float* w_in    = (const float*)d_in[3];
    const float* b_in    = (const float*)d_in[4];
    const float* gru_wx  = (const float*)d_in[5];
    const float* gru_wh  = (const float*)d_in[6];
    const float* ln_att_g= (const float*)d_in[7];
    const float* ln_att_b= (const float*)d_in[8];
    const float* wq = (const float*)d_in[9];
    const float* bq = (const float*)d_in[10];
    const float* wk = (const float*)d_in[11];
    const float* bk = (const float*)d_in[12];
    const float* wv = (const float*)d_in[13];
    const float* bv = (const float*)d_in[14];
    const float* wo = (const float*)d_in[15];
    const float* bo = (const float*)d_in[16];
    const float* ln_m_g = (const float*)d_in[17];
    const float* ln_m_b = (const float*)d_in[18];
    const float* w_m1 = (const float*)d_in[19];
    const float* b_m1 = (const float*)d_in[20];
    const float* w_m2 = (const float*)d_in[21];
    const float* b_m2 = (const float*)d_in[22];
    const float* ln_out_g = (const float*)d_in[23];
    const float* ln_out_b = (const float*)d_in[24];
    const float* w_out = (const float*)d_in[25];
    const float* b_out = (const float*)d_in[26];
    float* out = (float*)d_out;

    float* x  = (float*)d_ws;                       // [B,T,F,C]
    float* hs = x + (size_t)B_*T_*F_*C_;            // [B,T,F,C]

    k_conv_in<<<B_*T_, 128, 0, stream>>>(input, ln_in_g, ln_in_b, w_in, b_in, x);
    k_gru<<<192, 64, 0, stream>>>(x, gru_wx, gru_wh, hs, out);
    k_tail<<<B_*T_, 256, 0, stream>>>(x, hs, input, ln_att_g, ln_att_b,
        wq, bq, wk, bk, wv, bv, wo, bo, ln_m_g, ln_m_b, w_m1, b_m1, w_m2, b_m2,
        ln_out_g, ln_out_b, w_out, b_out, out);
}

// Round 6
// 908.147 us; speedup vs baseline: 1.2205x; 1.2205x over previous
//
#include <hip/hip_runtime.h>
#include <math.h>

#define B_ 8
#define T_ 1000
#define F_ 96
#define C_ 16
#define D_ 64
#define EPS_ 1e-5f
#define CH_ 40   // GRU time-chunk (1000 = 25*40; 40*64 floats = 10 insts of 1024B)

__device__ __forceinline__ float gelu_erf(float v){
    return 0.5f*v*(1.0f+erff(v*0.70710678118654752440f));
}
__device__ __forceinline__ float dot4(float4 a, float4 b){
    return a.x*b.x + a.y*b.y + a.z*b.z + a.w*b.w;
}
__device__ __forceinline__ float fast_sigmoid(float a){
    return __builtin_amdgcn_rcpf(1.f + __expf(-a));
}
__device__ __forceinline__ float fast_tanh(float a){
    return 1.f - 2.f*__builtin_amdgcn_rcpf(1.f + __expf(2.f*a));
}
// precise LDS-only fence: orders DS ops without draining vmcnt
__device__ __forceinline__ void ds_fence(){
    asm volatile("s_waitcnt lgkmcnt(0)" ::: "memory");
}
__device__ __forceinline__ void vm_fence(){
    asm volatile("s_waitcnt vmcnt(0)" ::: "memory");
}
// wave-synchronous LDS fence for k_tail
__device__ __forceinline__ void wsync(){
    __builtin_amdgcn_wave_barrier();
    asm volatile("s_waitcnt lgkmcnt(0)" ::: "memory");
    __builtin_amdgcn_wave_barrier();
}

// ---------------- Kernel A: conv_in -> x [B,T,F,C] ----------------
__global__ __launch_bounds__(128) void k_conv_in(
    const float* __restrict__ in, const float* __restrict__ g, const float* __restrict__ bb,
    const float* __restrict__ w_in, const float* __restrict__ b_in,
    float* __restrict__ x)
{
    int bt = blockIdx.x; int b = bt / T_; int t = bt % T_;
    int tid = threadIdx.x;
    __shared__ float r0[128], r1[128], r2[128], r3[128];
    float i0=0.f, i1=0.f;
    size_t base0 = ((size_t)(b*2+0)*T_ + t)*F_;
    size_t base1 = ((size_t)(b*2+1)*T_ + t)*F_;
    if (tid < F_){ i0 = in[base0+tid]; i1 = in[base1+tid]; }
    r0[tid]=i0; r1[tid]=i0*i0; r2[tid]=i1; r3[tid]=i1*i1;
    __syncthreads();
    for (int s=64; s>0; s>>=1){
        if (tid < s){ r0[tid]+=r0[tid+s]; r1[tid]+=r1[tid+s]; r2[tid]+=r2[tid+s]; r3[tid]+=r3[tid+s]; }
        __syncthreads();
    }
    float m0 = r0[0]*(1.f/F_), m1 = r2[0]*(1.f/F_);
    float ri0 = rsqrtf(r1[0]*(1.f/F_) - m0*m0 + EPS_);
    float ri1 = rsqrtf(r3[0]*(1.f/F_) - m1*m1 + EPS_);
    if (tid < F_){
        float gg = g[tid], b0 = bb[tid];
        float y0 = (i0-m0)*ri0*gg + b0;
        float y1 = (i1-m1)*ri1*gg + b0;
        float xv[16];
        #pragma unroll
        for (int c=0;c<C_;++c){
            xv[c] = gelu_erf(w_in[c*2+0]*y0 + w_in[c*2+1]*y1 + b_in[c]);
        }
        float4* xp = (float4*)(x + (((size_t)b*T_+t)*F_ + tid)*C_);
        xp[0] = make_float4(xv[0],xv[1],xv[2],xv[3]);
        xp[1] = make_float4(xv[4],xv[5],xv[6],xv[7]);
        xp[2] = make_float4(xv[8],xv[9],xv[10],xv[11]);
        xp[3] = make_float4(xv[12],xv[13],xv[14],xv[15]);
    }
}

// ---------------- Kernel B: ConvGRU — 4 chains/wave; x staged to LDS by DMA ----------------
// 192 blocks x 64 threads. lane = ch*16 + c; chain = (b, f0+ch).
// x[t] for the 4-chain band is 64 contiguous floats in global; global_load_lds width=16
// with lane-order (tq=lane>>4, i2=lane&15) lands chunk rows at xb[tloc*64 + i2*4] —
// exactly the [t][ch*16+c] layout the step loop reads. One vmcnt wait per 40 steps.
__global__ __launch_bounds__(64) void k_gru(
    const float* __restrict__ x, const float* __restrict__ wx, const float* __restrict__ wh,
    float* __restrict__ hs, float* __restrict__ d_out)
{
    int blk = blockIdx.x;
    int b = blk / 24, f0 = (blk % 24) * 4;
    int lane = threadIdx.x;
    int c = lane & 15, ch = lane >> 4;
    int f = f0 + ch;

    __shared__ __align__(16) float xb[2][CH_*64];
    __shared__ float hsh[64];

    float4 Wxz[4], Wxr[4], Wxn[4], Whz[4], Whr[4], Whn[4];
    #pragma unroll
    for (int q=0;q<4;++q){
        Wxz[q] = *(const float4*)(wx + ( 0+c)*16 + 4*q);
        Wxr[q] = *(const float4*)(wx + (16+c)*16 + 4*q);
        Wxn[q] = *(const float4*)(wx + (32+c)*16 + 4*q);
        Whz[q] = *(const float4*)(wh + ( 0+c)*16 + 4*q);
        Whr[q] = *(const float4*)(wh + (16+c)*16 + 4*q);
        Whn[q] = *(const float4*)(wh + (32+c)*16 + 4*q);
    }

    const float* gbase = x + ((size_t)b*T_)*(F_*C_) + f0*C_;
    int tq = lane >> 4, i2 = lane & 15;

    // stage chunk starting at t0 into buffer bi (10 x 1024B DMA insts)
    #define STAGE(t0, bi) { \
        _Pragma("unroll") \
        for (int i=0;i<CH_/4;++i){ \
            const float* gp = gbase + (size_t)((t0) + i*4 + tq)*(F_*C_) + i2*4; \
            __builtin_amdgcn_global_load_lds( \
                (const __attribute__((address_space(1))) void*)gp, \
                (__attribute__((address_space(3))) void*)(&xb[bi][i*256]), \
                16, 0, 0); \
        } \
    }

    STAGE(0, 0);

    float4 h4[4];
    #pragma unroll
    for (int q=0;q<4;++q) h4[q] = make_float4(0.f,0.f,0.f,0.f);
    float hc = 0.f;

    const float* hrow = hsh + ch*16;
    size_t hsb = (size_t)b*T_*(F_*C_) + f0*C_ + lane;   // += 1536 per t (coalesced 256B/wave)

    vm_fence();   // chunk 0 resident

    for (int k=0; k<T_/CH_; ++k){
        if (k+1 < T_/CH_) STAGE((k+1)*CH_, (k+1)&1);
        const float* xcur = xb[k&1];
        for (int tl=0; tl<CH_; ++tl){
            int t = k*CH_ + tl;
            float4 cur0 = *(const float4*)(xcur + tl*64 + ch*16 + 0);
            float4 cur1 = *(const float4*)(xcur + tl*64 + ch*16 + 4);
            float4 cur2 = *(const float4*)(xcur + tl*64 + ch*16 + 8);
            float4 cur3 = *(const float4*)(xcur + tl*64 + ch*16 + 12);
            float zx = dot4(Wxz[0],cur0)+dot4(Wxz[1],cur1)+dot4(Wxz[2],cur2)+dot4(Wxz[3],cur3);
            float rx = dot4(Wxr[0],cur0)+dot4(Wxr[1],cur1)+dot4(Wxr[2],cur2)+dot4(Wxr[3],cur3);
            float nxv= dot4(Wxn[0],cur0)+dot4(Wxn[1],cur1)+dot4(Wxn[2],cur2)+dot4(Wxn[3],cur3);
            float zh = dot4(Whz[0],h4[0])+dot4(Whz[1],h4[1])+dot4(Whz[2],h4[2])+dot4(Whz[3],h4[3]);
            float rh = dot4(Whr[0],h4[0])+dot4(Whr[1],h4[1])+dot4(Whr[2],h4[2])+dot4(Whr[3],h4[3]);
            float nh = dot4(Whn[0],h4[0])+dot4(Whn[1],h4[1])+dot4(Whn[2],h4[2])+dot4(Whn[3],h4[3]);
            float z = fast_sigmoid(zx+zh);
            float r = fast_sigmoid(rx+rh);
            float n = fast_tanh(nxv + r*nh);
            float hn = n + z*(hc - n);
            hc = hn;
            hsh[lane] = hn;                      // ds_write (critical path)
            hs[hsb + (size_t)t*(F_*C_)] = hn;    // global store (not waited)
            ds_fence();                          // lgkmcnt(0) only
            #pragma unroll
            for (int q=0;q<4;++q) h4[q] = *(const float4*)(hrow + 4*q);  // broadcast
        }
        vm_fence();   // next chunk's DMA (issued a full chunk ago) + stores drained
    }
    #undef STAGE
    d_out[(size_t)B_*2*T_*F_ + ((size_t)b*C_ + c)*F_ + f] = hc;
}

// ---------------- Kernel C: fused attention + MLP + conv_out ----------------
// LDS map (floats). All float4-read bases 16B aligned; strides chosen for <=2-way banks.
#define OX2   0        // x2/y/x3 [96][16]  f*16+c            1536
#define OYM   1536     // ymean [24][16]  m*16+c               384
#define OKL   1920     // k_long [24][68]                     1632
#define OVL   3552     // v_long [24][68]                     1632
#define OWQ   5184     // wq as float4 tiles: f4idx=c4*64+d   1024
#define OWK   6208
#define OWV   7232
#define OWO   8256     // wo as float4 tiles: f4idx=dd4*16+cc 1024
#define OWM1  9280     // [16][16]                             256
#define OWM2  9536     //                                      256
#define OMEA  9792     // 16
#define ORST  9808     // 16
#define OSC   9824     // LN partial scratch 512
#define OWS   10336    // per-wave scratch x4, stride 672: K[4*68] Q[4*68] A[112+pad]
#define WSSTR 672
#define TOTF  (OWS + 4*WSSTR)   // 13024 floats = 52096 B

__device__ __forceinline__ void ln_stats16(float* S, int tid){
    int c = tid & 15, g = tid >> 4;
    float s=0.f, q=0.f;
    #pragma unroll
    for (int i=0;i<6;++i){
        float v = S[OX2 + (g*6+i)*16 + c];
        s += v; q += v*v;
    }
    S[OSC + g*16 + c] = s;
    S[OSC + 256 + g*16 + c] = q;
    __syncthreads();
    if (tid < 16){
        float Sm=0.f, Q=0.f;
        #pragma unroll
        for (int g2=0; g2<16; ++g2){
            Sm += S[OSC + g2*16 + tid];
            Q  += S[OSC + 256 + g2*16 + tid];
        }
        float m = Sm*(1.f/96.f);
        S[OMEA+tid] = m;
        S[ORST+tid] = rsqrtf(Q*(1.f/96.f) - m*m + EPS_);
    }
    __syncthreads();
}

__global__ __launch_bounds__(256) void k_tail(
    const float* __restrict__ x, const float* __restrict__ hs, const float* __restrict__ input,
    const float* __restrict__ ln_att_g, const float* __restrict__ ln_att_b,
    const float* __restrict__ wq, const float* __restrict__ bq,
    const float* __restrict__ wk, const float* __restrict__ bk,
    const float* __restrict__ wv, const float* __restrict__ bv,
    const float* __restrict__ wo, const float* __restrict__ bo,
    const float* __restrict__ ln_m_g, const float* __restrict__ ln_m_b,
    const float* __restrict__ wm1, const float* __restrict__ bm1,
    const float* __restrict__ wm2, const float* __restrict__ bm2,
    const float* __restrict__ ln_o_g, const float* __restrict__ ln_o_b,
    const float* __restrict__ w_out, const float* __restrict__ b_out,
    float* __restrict__ out)
{
    int bt = blockIdx.x; int b = bt / T_; int t = bt % T_;
    int tid = threadIdx.x;
    int w = tid >> 6, lane = tid & 63;
    __shared__ float S[TOTF];
    float4* X2f4 = (float4*)(S + OX2);
    float4* YM4  = (float4*)(S + OYM);
    const float4* WQ4 = (const float4*)(S + OWQ);
    const float4* WK4 = (const float4*)(S + OWK);
    const float4* WV4 = (const float4*)(S + OWV);
    const float4* WO4 = (const float4*)(S + OWO);

    size_t xbase = ((size_t)b*T_ + t)*(size_t)(F_*C_);

    // lane-resident biases (lane = d for qkv phases; lane&15 = c for out-proj)
    float bq_r = bq[lane], bk_r = bk[lane], bv_r = bv[lane];
    float bo_r = bo[lane & 15];

    // P0: x2 = x + hs (float4 coalesced); stage weights as float4 tiles
    {
        const float4* xg = (const float4*)(x + xbase);
        const float4* hg = (const float4*)(hs + xbase);
        for (int i4 = tid; i4 < 384; i4 += 256){
            float4 a = xg[i4], h = hg[i4];
            X2f4[i4] = make_float4(a.x+h.x, a.y+h.y, a.z+h.z, a.w+h.w);
        }
        // wq/wk/wv global [64][16]: tid -> d=tid>>2, c4=tid&3 ; store f4idx c4*64+d
        {
            int d = tid >> 2, c4 = tid & 3;
            ((float4*)(S+OWQ))[c4*64 + d] = ((const float4*)wq)[tid];
            ((float4*)(S+OWK))[c4*64 + d] = ((const float4*)wk)[tid];
            ((float4*)(S+OWV))[c4*64 + d] = ((const float4*)wv)[tid];
        }
        // wo global [16][64]: tid -> c=tid>>4, dd4=tid&15 ; store f4idx dd4*16+c
        {
            int c2 = tid >> 4, dd4 = tid & 15;
            ((float4*)(S+OWO))[dd4*16 + c2] = ((const float4*)wo)[tid];
        }
        S[OWM1 + tid] = wm1[tid];
        S[OWM2 + tid] = wm2[tid];
    }
    __syncthreads();

    // P1/P2: attention LN
    ln_stats16(S, tid);
    for (int i4 = tid; i4 < 384; i4 += 256){
        int f = i4 >> 2, c4 = i4 & 3;
        float4 v = X2f4[i4];
        float4 m4 = *(float4*)(S + OMEA + 4*c4);
        float4 r4 = *(float4*)(S + ORST + 4*c4);
        float gg = ln_att_g[f], b2 = ln_att_b[f];
        v.x = (v.x - m4.x)*r4.x*gg + b2;
        v.y = (v.y - m4.y)*r4.y*gg + b2;
        v.z = (v.z - m4.z)*r4.z*gg + b2;
        v.w = (v.w - m4.w)*r4.w*gg + b2;
        X2f4[i4] = v;
    }
    __syncthreads();

    // P3: segment means
    for (int i4 = tid; i4 < 96; i4 += 256){
        int m = i4 >> 2, c4 = i4 & 3;
        float4 a0 = X2f4[(4*m+0)*4 + c4];
        float4 a1 = X2f4[(4*m+1)*4 + c4];
        float4 a2 = X2f4[(4*m+2)*4 + c4];
        float4 a3 = X2f4[(4*m+3)*4 + c4];
        YM4[m*4 + c4] = make_float4(0.25f*(a0.x+a1.x+a2.x+a3.x), 0.25f*(a0.y+a1.y+a2.y+a3.y),
                                    0.25f*(a0.z+a1.z+a2.z+a3.z), 0.25f*(a0.w+a1.w+a2.w+a3.w));
    }
    __syncthreads();

    // P4: k_long/v_long — wave w computes m = 6w..6w+5, lane = d
    {
        int m0 = 6*w;
        float ak[6], av[6];
        #pragma unroll
        for (int j=0;j<6;++j){ ak[j] = bk_r; av[j] = bv_r; }
        #pragma unroll
        for (int c4=0;c4<4;++c4){
            float4 k4 = WK4[c4*64 + lane];
            float4 v4 = WV4[c4*64 + lane];
            #pragma unroll
            for (int j=0;j<6;++j){
                float4 y4 = YM4[(m0+j)*4 + c4];     // broadcast
                ak[j] += dot4(k4, y4);
                av[j] += dot4(v4, y4);
            }
        }
        #pragma unroll
        for (int j=0;j<6;++j){
            S[OKL + (m0+j)*68 + lane] = ak[j];
            S[OVL + (m0+j)*68 + lane] = av[j];
        }
    }
    __syncthreads();

    // P5: attention — wave w owns segments 6w..6w+5; wave-synchronous
    float* wsK = S + OWS + w*WSSTR;
    float* wsQ = wsK + 272;
    float* wsA = wsK + 544;                 // transposed: a[key j][r]
    float4* wsA4 = (float4*)wsA;
    for (int si=0; si<6; ++si){
        int s = 6*w + si;
        // qkv for the 4 rows of this segment (lane = d)
        float aq[4], ak2[4], av2[4];
        #pragma unroll
        for (int r=0;r<4;++r){ aq[r]=bq_r; ak2[r]=bk_r; av2[r]=bv_r; }
        #pragma unroll
        for (int c4=0;c4<4;++c4){
            float4 q4 = WQ4[c4*64 + lane];
            float4 k4 = WK4[c4*64 + lane];
            float4 v4 = WV4[c4*64 + lane];
            #pragma unroll
            for (int r=0;r<4;++r){
                float4 y4 = X2f4[(4*s+r)*4 + c4];    // broadcast
                aq[r] += dot4(q4, y4);
                ak2[r] += dot4(k4, y4);
                av2[r] += dot4(v4, y4);
            }
        }
        #pragma unroll
        for (int r=0;r<4;++r){
            wsQ[r*68 + lane] = aq[r];
            wsK[r*68 + lane] = ak2[r];
        }
        wsync();
        // scores + softmax: lane = (r2 = lane>>4, jj = lane&15); keys jj (4 loc + 12 long) and jj+16
        {
            int r2 = lane >> 4, jj = lane & 15;
            const float* qrow = wsQ + r2*68;
            const float* k1 = (jj < 4) ? (wsK + jj*68) : (S + OKL + (jj-4)*68);
            const float* k2p = S + OKL + (jj+12)*68;   // valid only jj<12 (guarded below)
            float a1 = 0.f, a2 = 0.f;
            #pragma unroll
            for (int dd4=0; dd4<16; ++dd4){
                float4 q4  = *(const float4*)(qrow + 4*dd4);
                float4 k14 = *(const float4*)(k1   + 4*dd4);
                float4 k24 = *(const float4*)(k2p  + 4*dd4);
                a1 += dot4(q4, k14);
                a2 += dot4(q4, k24);
            }
            float s1 = a1*0.125f;
            float s2 = (jj < 12) ? a2*0.125f : -INFINITY;
            float mx = fmaxf(s1, s2);
            #pragma unroll
            for (int off=8; off; off>>=1) mx = fmaxf(mx, __shfl_xor(mx, off, 16));
            float p1 = expf(s1 - mx);
            float p2 = (jj < 12) ? expf(s2 - mx) : 0.f;
            float sm = p1 + p2;
            #pragma unroll
            for (int off=8; off; off>>=1) sm += __shfl_xor(sm, off, 16);
            float inv = 1.f/sm;
            wsA[jj*4 + r2] = p1*inv;
            if (jj < 12) wsA[(16+jj)*4 + r2] = p2*inv;
        }
        wsync();
        // o = a_loc·v_loc + a_long·v_long  (lane = d); overwrite wsK rows with o
        {
            float o0, o1, o2, o3;
            float4 aj = wsA4[0];
            o0 = aj.x*av2[0]; o1 = aj.y*av2[0]; o2 = aj.z*av2[0]; o3 = aj.w*av2[0];
            #pragma unroll
            for (int j=1;j<4;++j){
                aj = wsA4[j];
                o0 += aj.x*av2[j]; o1 += aj.y*av2[j]; o2 += aj.z*av2[j]; o3 += aj.w*av2[j];
            }
            #pragma unroll
            for (int m=0;m<24;++m){
                float vm = S[OVL + m*68 + lane];
                float4 am = wsA4[4+m];              // broadcast
                o0 += am.x*vm; o1 += am.y*vm; o2 += am.z*vm; o3 += am.w*vm;
            }
            wsync();                                 // everyone done reading wsK (scores)
            wsK[0*68 + lane] = o0;
            wsK[1*68 + lane] = o1;
            wsK[2*68 + lane] = o2;
            wsK[3*68 + lane] = o3;
        }
        wsync();
        // out-proj + residual -> x3 written into X2 (rows owned by this wave)
        {
            int r2 = lane >> 4, cc = lane & 15;
            const float* orow = wsK + r2*68;
            float acc = bo_r;
            #pragma unroll
            for (int dd4=0; dd4<16; ++dd4){
                float4 w4 = WO4[dd4*16 + cc];
                float4 o4 = *(const float4*)(orow + 4*dd4);  // broadcast per r-group
                acc += dot4(w4, o4);
            }
            int fc = 4*s + r2;
            float resid = x[xbase + fc*16 + cc] + hs[xbase + fc*16 + cc];
            S[OX2 + cc + fc*16] = resid + acc;
        }
        wsync();
    }
    __syncthreads();

    // P6: MLP
    ln_stats16(S, tid);
    for (int i4 = tid; i4 < 384; i4 += 256){
        int f = i4 >> 2, c4 = i4 & 3;
        float4 v = X2f4[i4];
        float4 m4 = *(float4*)(S + OMEA + 4*c4);
        float4 r4 = *(float4*)(S + ORST + 4*c4);
        float gg = ln_m_g[f], b2 = ln_m_b[f];
        v.x = (v.x - m4.x)*r4.x*gg + b2;
        v.y = (v.y - m4.y)*r4.y*gg + b2;
        v.z = (v.z - m4.z)*r4.z*gg + b2;
        v.w = (v.w - m4.w)*r4.w*gg + b2;
        ((float4*)(S+OKL))[i4] = v;                   // ynorm in KL region
    }
    __syncthreads();
    for (int i4 = tid; i4 < 384; i4 += 256){
        int f = i4 >> 2, cb = i4 & 3;
        float4 acc = *(const float4*)(bm1 + 4*cb);
        #pragma unroll
        for (int c4=0;c4<4;++c4){
            float4 yn4 = ((float4*)(S+OKL))[f*4 + c4];
            float4 w0 = *(float4*)(S + OWM1 + (4*cb+0)*16 + 4*c4);
            float4 w1 = *(float4*)(S + OWM1 + (4*cb+1)*16 + 4*c4);
            float4 w2 = *(float4*)(S + OWM1 + (4*cb+2)*16 + 4*c4);
            float4 w3 = *(float4*)(S + OWM1 + (4*cb+3)*16 + 4*c4);
            acc.x += dot4(w0, yn4); acc.y += dot4(w1, yn4);
            acc.z += dot4(w2, yn4); acc.w += dot4(w3, yn4);
        }
        acc.x = gelu_erf(acc.x); acc.y = gelu_erf(acc.y);
        acc.z = gelu_erf(acc.z); acc.w = gelu_erf(acc.w);
        ((float4*)(S+OVL))[i4] = acc;                 // y1 in VL region
    }
    __syncthreads();
    for (int i4 = tid; i4 < 384; i4 += 256){
        int f = i4 >> 2, cb = i4 & 3;
        float4 acc = *(const float4*)(bm2 + 4*cb);
        #pragma unroll
        for (int c4=0;c4<4;++c4){
            float4 y14 = ((float4*)(S+OVL))[f*4 + c4];
            float4 w0 = *(float4*)(S + OWM2 + (4*cb+0)*16 + 4*c4);
            float4 w1 = *(float4*)(S + OWM2 + (4*cb+1)*16 + 4*c4);
            float4 w2 = *(float4*)(S + OWM2 + (4*cb+2)*16 + 4*c4);
            float4 w3 = *(float4*)(S + OWM2 + (4*cb+3)*16 + 4*c4);
            acc.x += dot4(w0, y14); acc.y += dot4(w1, y14);
            acc.z += dot4(w2, y14); acc.w += dot4(w3, y14);
        }
        float4 xv = X2f4[i4];
        X2f4[i4] = make_float4(xv.x+acc.x, xv.y+acc.y, xv.z+acc.z, xv.w+acc.w);
    }
    __syncthreads();

    // P7: conv_out + outer residual
    ln_stats16(S, tid);
    if (tid < 192){
        int ch = tid >= 96, f = tid - 96*ch;
        float gg = ln_o_g[f], b2 = ln_o_b[f];
        float acc = b_out[ch];
        #pragma unroll
        for (int c4=0;c4<4;++c4){
            float4 x4 = X2f4[f*4 + c4];
            float4 m4 = *(float4*)(S + OMEA + 4*c4);
            float4 r4 = *(float4*)(S + ORST + 4*c4);
            float4 w4 = *(const float4*)(w_out + ch*16 + 4*c4);
            float4 tm;
            tm.x = (x4.x - m4.x)*r4.x*gg + b2;
            tm.y = (x4.y - m4.y)*r4.y*gg + b2;
            tm.z = (x4.z - m4.z)*r4.z*gg + b2;
            tm.w = (x4.w - m4.w)*r4.w*gg + b2;
            acc += dot4(w4, tm);
        }
        size_t oidx = ((size_t)(b*2+ch)*T_ + t)*F_ + f;
        out[oidx] = input[oidx] + tanhf(acc);
    }
}

extern "C" void kernel_launch(void* const* d_in, const int* in_sizes, int n_in,
                              void* d_out, int out_size, void* d_ws, size_t ws_size,
                              hipStream_t stream)
{
    const float* input   = (const float*)d_in[0];
    const float* ln_in_g = (const float*)d_in[1];
    const float* ln_in_b = (const float*)d_in[2];
    const float* w_in    = (const float*)d_in[3];
    const float* b_in    = (const float*)d_in[4];
    const float* gru_wx  = (const float*)d_in[5];
    const float* gru_wh  = (const float*)d_in[6];
    const float* ln_att_g= (const float*)d_in[7];
    const float* ln_att_b= (const float*)d_in[8];
    const float* wq = (const float*)d_in[9];
    const float* bq = (const float*)d_in[10];
    const float* wk = (const float*)d_in[11];
    const float* bk = (const float*)d_in[12];
    const float* wv = (const float*)d_in[13];
    const float* bv = (const float*)d_in[14];
    const float* wo = (const float*)d_in[15];
    const float* bo = (const float*)d_in[16];
    const float* ln_m_g = (const float*)d_in[17];
    const float* ln_m_b = (const float*)d_in[18];
    const float* w_m1 = (const float*)d_in[19];
    const float* b_m1 = (const float*)d_in[20];
    const float* w_m2 = (const float*)d_in[21];
    const float* b_m2 = (const float*)d_in[22];
    const float* ln_out_g = (const float*)d_in[23];
    const float* ln_out_b = (const float*)d_in[24];
    const float* w_out = (const float*)d_in[25];
    const float* b_out = (const float*)d_in[26];
    float* out = (float*)d_out;

    float* x  = (float*)d_ws;                       // [B,T,F,C]
    float* hs = x + (size_t)B_*T_*F_*C_;            // [B,T,F,C]

    k_conv_in<<<B_*T_, 128, 0, stream>>>(input, ln_in_g, ln_in_b, w_in, b_in, x);
    k_gru<<<192, 64, 0, stream>>>(x, gru_wx, gru_wh, hs, out);
    k_tail<<<B_*T_, 256, 0, stream>>>(x, hs, input, ln_att_g, ln_att_b,
        wq, bq, wk, bk, wv, bv, wo, bo, ln_m_g, ln_m_b, w_m1, b_m1, w_m2, b_m2,
        ln_out_g, ln_out_b, w_out, b_out, out);
}

// Round 7
// 777.395 us; speedup vs baseline: 1.4258x; 1.1682x over previous
//
#include <hip/hip_runtime.h>
#include <math.h>

#define B_ 8
#define T_ 1000
#define F_ 96
#define C_ 16
#define D_ 64
#define EPS_ 1e-5f
#define CH_ 40   // GRU time-chunk (1000 = 25*40)

__device__ __forceinline__ float gelu_erf(float v){
    return 0.5f*v*(1.0f+erff(v*0.70710678118654752440f));
}
__device__ __forceinline__ float dot4(float4 a, float4 b){
    return a.x*b.x + a.y*b.y + a.z*b.z + a.w*b.w;
}
__device__ __forceinline__ float fast_sigmoid(float a){
    return __builtin_amdgcn_rcpf(1.f + __expf(-a));
}
__device__ __forceinline__ float fast_tanh(float a){
    return 1.f - 2.f*__builtin_amdgcn_rcpf(1.f + __expf(2.f*a));
}
// wave-synchronous LDS fence for k_tail
__device__ __forceinline__ void wsync(){
    __builtin_amdgcn_wave_barrier();
    asm volatile("s_waitcnt lgkmcnt(0)" ::: "memory");
    __builtin_amdgcn_wave_barrier();
}

// ---------------- Kernel A: conv_in -> x [B,T,F,C] ----------------
__global__ __launch_bounds__(128) void k_conv_in(
    const float* __restrict__ in, const float* __restrict__ g, const float* __restrict__ bb,
    const float* __restrict__ w_in, const float* __restrict__ b_in,
    float* __restrict__ x)
{
    int bt = blockIdx.x; int b = bt / T_; int t = bt % T_;
    int tid = threadIdx.x;
    __shared__ float r0[128], r1[128], r2[128], r3[128];
    float i0=0.f, i1=0.f;
    size_t base0 = ((size_t)(b*2+0)*T_ + t)*F_;
    size_t base1 = ((size_t)(b*2+1)*T_ + t)*F_;
    if (tid < F_){ i0 = in[base0+tid]; i1 = in[base1+tid]; }
    r0[tid]=i0; r1[tid]=i0*i0; r2[tid]=i1; r3[tid]=i1*i1;
    __syncthreads();
    for (int s=64; s>0; s>>=1){
        if (tid < s){ r0[tid]+=r0[tid+s]; r1[tid]+=r1[tid+s]; r2[tid]+=r2[tid+s]; r3[tid]+=r3[tid+s]; }
        __syncthreads();
    }
    float m0 = r0[0]*(1.f/F_), m1 = r2[0]*(1.f/F_);
    float ri0 = rsqrtf(r1[0]*(1.f/F_) - m0*m0 + EPS_);
    float ri1 = rsqrtf(r3[0]*(1.f/F_) - m1*m1 + EPS_);
    if (tid < F_){
        float gg = g[tid], b0 = bb[tid];
        float y0 = (i0-m0)*ri0*gg + b0;
        float y1 = (i1-m1)*ri1*gg + b0;
        float xv[16];
        #pragma unroll
        for (int c=0;c<C_;++c){
            xv[c] = gelu_erf(w_in[c*2+0]*y0 + w_in[c*2+1]*y1 + b_in[c]);
        }
        float4* xp = (float4*)(x + (((size_t)b*T_+t)*F_ + tid)*C_);
        xp[0] = make_float4(xv[0],xv[1],xv[2],xv[3]);
        xp[1] = make_float4(xv[4],xv[5],xv[6],xv[7]);
        xp[2] = make_float4(xv[8],xv[9],xv[10],xv[11]);
        xp[3] = make_float4(xv[12],xv[13],xv[14],xv[15]);
    }
}

// ---------------- Kernel B: ConvGRU — producer/consumer waves, swizzle h-exchange ----
// 192 blocks x 128 threads (2 waves). Block = (b, 4 f-chains). lane = ch*16 + c.
// Wave 1 (producer): gx = Wx·x(t) for each chunk of 40 steps -> LDS (double-buffered).
// Wave 0 (consumer): pure h-recurrence. h lives one-channel-per-lane; the 16-wide
// h broadcast is 15 ds_swizzle XOR ops (no fence, no barrier, pure dataflow);
// weights pre-permuted per lane: Wh'[m] = Wh[c][c^m].
__global__ __launch_bounds__(128) void k_gru(
    const float* __restrict__ x, const float* __restrict__ wx, const float* __restrict__ wh,
    float* __restrict__ hs, float* __restrict__ d_out)
{
    int blk = blockIdx.x;
    int b = blk / 24, f0 = (blk % 24) * 4;
    int tid = threadIdx.x;
    int wave = tid >> 6, lane = tid & 63;
    int c = lane & 15, ch = lane >> 4;
    int f = f0 + ch;

    __shared__ float GZ[2][CH_*64];
    __shared__ float GR[2][CH_*64];
    __shared__ float GN[2][CH_*64];

    if (wave == 1){
        // ---------------- producer ----------------
        float4 Wxz[4], Wxr[4], Wxn[4];
        #pragma unroll
        for (int q=0;q<4;++q){
            Wxz[q] = *(const float4*)(wx + ( 0+c)*16 + 4*q);
            Wxr[q] = *(const float4*)(wx + (16+c)*16 + 4*q);
            Wxn[q] = *(const float4*)(wx + (32+c)*16 + 4*q);
        }
        const float* gb0 = x + (size_t)b*T_*(F_*C_) + f*C_;

        #define PRODUCE(K, BF) { \
            _Pragma("unroll 4") \
            for (int tl=0; tl<CH_; ++tl){ \
                const float* xp2 = gb0 + (size_t)((K)*CH_ + tl)*(F_*C_); \
                float4 x0 = *(const float4*)(xp2 + 0); \
                float4 x1 = *(const float4*)(xp2 + 4); \
                float4 x2 = *(const float4*)(xp2 + 8); \
                float4 x3 = *(const float4*)(xp2 + 12); \
                float zx = dot4(Wxz[0],x0)+dot4(Wxz[1],x1)+dot4(Wxz[2],x2)+dot4(Wxz[3],x3); \
                float rx = dot4(Wxr[0],x0)+dot4(Wxr[1],x1)+dot4(Wxr[2],x2)+dot4(Wxr[3],x3); \
                float nx = dot4(Wxn[0],x0)+dot4(Wxn[1],x1)+dot4(Wxn[2],x2)+dot4(Wxn[3],x3); \
                GZ[BF][tl*64+lane]=zx; GR[BF][tl*64+lane]=rx; GN[BF][tl*64+lane]=nx; \
            } }

        PRODUCE(0, 0);
        __syncthreads();
        for (int k=0; k<T_/CH_; ++k){
            if (k+1 < T_/CH_){
                if ((k+1)&1){ PRODUCE(k+1, 1); } else { PRODUCE(k+1, 0); }
            }
            __syncthreads();
        }
        #undef PRODUCE
    } else {
        // ---------------- consumer ----------------
        float Whz[16], Whr[16], Whn[16];
        for (int m=0;m<16;++m){
            int k2 = c ^ m;
            Whz[m] = wh[( 0+c)*16 + k2];
            Whr[m] = wh[(16+c)*16 + k2];
            Whn[m] = wh[(32+c)*16 + k2];
        }
        float hc = 0.f;
        size_t hsb = (size_t)b*T_*(F_*C_) + f0*C_ + lane;
        __syncthreads();

        #define SWZL(m) __int_as_float(__builtin_amdgcn_ds_swizzle(__float_as_int(hc), ((m)<<10)|0x1F))
        for (int k=0; k<T_/CH_; ++k){
            const float* gzp = GZ[k&1];
            const float* grp = GR[k&1];
            const float* gnp = GN[k&1];
            for (int tl=0; tl<CH_; ++tl){
                int idx = tl*64 + lane;
                float gzv = gzp[idx], grv = grp[idx], gnv = gnp[idx];
                float hx0 = hc;
                float hx1 = SWZL(1),  hx2 = SWZL(2),  hx3 = SWZL(3);
                float hx4 = SWZL(4),  hx5 = SWZL(5),  hx6 = SWZL(6),  hx7 = SWZL(7);
                float hx8 = SWZL(8),  hx9 = SWZL(9),  hx10= SWZL(10), hx11= SWZL(11);
                float hx12= SWZL(12), hx13= SWZL(13), hx14= SWZL(14), hx15= SWZL(15);
                float zh = ((Whz[0]*hx0 + Whz[1]*hx1) + (Whz[2]*hx2 + Whz[3]*hx3))
                         + ((Whz[4]*hx4 + Whz[5]*hx5) + (Whz[6]*hx6 + Whz[7]*hx7))
                         + ((Whz[8]*hx8 + Whz[9]*hx9) + (Whz[10]*hx10 + Whz[11]*hx11))
                         + ((Whz[12]*hx12 + Whz[13]*hx13) + (Whz[14]*hx14 + Whz[15]*hx15));
                float rh = ((Whr[0]*hx0 + Whr[1]*hx1) + (Whr[2]*hx2 + Whr[3]*hx3))
                         + ((Whr[4]*hx4 + Whr[5]*hx5) + (Whr[6]*hx6 + Whr[7]*hx7))
                         + ((Whr[8]*hx8 + Whr[9]*hx9) + (Whr[10]*hx10 + Whr[11]*hx11))
                         + ((Whr[12]*hx12 + Whr[13]*hx13) + (Whr[14]*hx14 + Whr[15]*hx15));
                float nh = ((Whn[0]*hx0 + Whn[1]*hx1) + (Whn[2]*hx2 + Whn[3]*hx3))
                         + ((Whn[4]*hx4 + Whn[5]*hx5) + (Whn[6]*hx6 + Whn[7]*hx7))
                         + ((Whn[8]*hx8 + Whn[9]*hx9) + (Whn[10]*hx10 + Whn[11]*hx11))
                         + ((Whn[12]*hx12 + Whn[13]*hx13) + (Whn[14]*hx14 + Whn[15]*hx15));
                float z = fast_sigmoid(gzv + zh);
                float r = fast_sigmoid(grv + rh);
                float n = fast_tanh(gnv + r*nh);
                hc = n + z*(hc - n);
                hs[hsb + (size_t)(k*CH_ + tl)*(F_*C_)] = hc;
            }
            __syncthreads();
        }
        #undef SWZL
        d_out[(size_t)B_*2*T_*F_ + ((size_t)b*C_ + c)*F_ + f] = hc;
    }
}

// ---------------- Kernel C: fused attention + MLP + conv_out ----------------
// LDS map (floats). All float4-read bases 16B aligned; strides chosen for <=2-way banks.
#define OX2   0        // x2/y/x3 [96][16]  f*16+c            1536
#define OYM   1536     // ymean [24][16]  m*16+c               384
#define OKL   1920     // k_long [24][68]                     1632
#define OVL   3552     // v_long [24][68]                     1632
#define OWQ   5184     // wq as float4 tiles: f4idx=c4*64+d   1024
#define OWK   6208
#define OWV   7232
#define OWO   8256     // wo as float4 tiles: f4idx=dd4*16+cc 1024
#define OWM1  9280     // [16][16]                             256
#define OWM2  9536     //                                      256
#define OMEA  9792     // 16
#define ORST  9808     // 16
#define OSC   9824     // LN partial scratch 512
#define OWS   10336    // per-wave scratch x4, stride 672: K[4*68] Q[4*68] A[112+pad]
#define WSSTR 672
#define TOTF  (OWS + 4*WSSTR)   // 13024 floats = 52096 B

__device__ __forceinline__ void ln_stats16(float* S, int tid){
    int c = tid & 15, g = tid >> 4;
    float s=0.f, q=0.f;
    #pragma unroll
    for (int i=0;i<6;++i){
        float v = S[OX2 + (g*6+i)*16 + c];
        s += v; q += v*v;
    }
    S[OSC + g*16 + c] = s;
    S[OSC + 256 + g*16 + c] = q;
    __syncthreads();
    if (tid < 16){
        float Sm=0.f, Q=0.f;
        #pragma unroll
        for (int g2=0; g2<16; ++g2){
            Sm += S[OSC + g2*16 + tid];
            Q  += S[OSC + 256 + g2*16 + tid];
        }
        float m = Sm*(1.f/96.f);
        S[OMEA+tid] = m;
        S[ORST+tid] = rsqrtf(Q*(1.f/96.f) - m*m + EPS_);
    }
    __syncthreads();
}

__global__ __launch_bounds__(256) void k_tail(
    const float* __restrict__ x, const float* __restrict__ hs, const float* __restrict__ input,
    const float* __restrict__ ln_att_g, const float* __restrict__ ln_att_b,
    const float* __restrict__ wq, const float* __restrict__ bq,
    const float* __restrict__ wk, const float* __restrict__ bk,
    const float* __restrict__ wv, const float* __restrict__ bv,
    const float* __restrict__ wo, const float* __restrict__ bo,
    const float* __restrict__ ln_m_g, const float* __restrict__ ln_m_b,
    const float* __restrict__ wm1, const float* __restrict__ bm1,
    const float* __restrict__ wm2, const float* __restrict__ bm2,
    const float* __restrict__ ln_o_g, const float* __restrict__ ln_o_b,
    const float* __restrict__ w_out, const float* __restrict__ b_out,
    float* __restrict__ out)
{
    int bt = blockIdx.x; int b = bt / T_; int t = bt % T_;
    int tid = threadIdx.x;
    int w = tid >> 6, lane = tid & 63;
    __shared__ float S[TOTF];
    float4* X2f4 = (float4*)(S + OX2);
    float4* YM4  = (float4*)(S + OYM);
    const float4* WQ4 = (const float4*)(S + OWQ);
    const float4* WK4 = (const float4*)(S + OWK);
    const float4* WV4 = (const float4*)(S + OWV);
    const float4* WO4 = (const float4*)(S + OWO);

    size_t xbase = ((size_t)b*T_ + t)*(size_t)(F_*C_);

    // lane-resident biases (lane = d for qkv phases; lane&15 = c for out-proj)
    float bq_r = bq[lane], bk_r = bk[lane], bv_r = bv[lane];
    float bo_r = bo[lane & 15];

    // P0: x2 = x + hs (float4 coalesced); stage weights as float4 tiles
    {
        const float4* xg = (const float4*)(x + xbase);
        const float4* hg = (const float4*)(hs + xbase);
        for (int i4 = tid; i4 < 384; i4 += 256){
            float4 a = xg[i4], h = hg[i4];
            X2f4[i4] = make_float4(a.x+h.x, a.y+h.y, a.z+h.z, a.w+h.w);
        }
        // wq/wk/wv global [64][16]: tid -> d=tid>>2, c4=tid&3 ; store f4idx c4*64+d
        {
            int d = tid >> 2, c4 = tid & 3;
            ((float4*)(S+OWQ))[c4*64 + d] = ((const float4*)wq)[tid];
            ((float4*)(S+OWK))[c4*64 + d] = ((const float4*)wk)[tid];
            ((float4*)(S+OWV))[c4*64 + d] = ((const float4*)wv)[tid];
        }
        // wo global [16][64]: tid -> c=tid>>4, dd4=tid&15 ; store f4idx dd4*16+c
        {
            int c2 = tid >> 4, dd4 = tid & 15;
            ((float4*)(S+OWO))[dd4*16 + c2] = ((const float4*)wo)[tid];
        }
        S[OWM1 + tid] = wm1[tid];
        S[OWM2 + tid] = wm2[tid];
    }
    __syncthreads();

    // P1/P2: attention LN
    ln_stats16(S, tid);
    for (int i4 = tid; i4 < 384; i4 += 256){
        int f = i4 >> 2, c4 = i4 & 3;
        float4 v = X2f4[i4];
        float4 m4 = *(float4*)(S + OMEA + 4*c4);
        float4 r4 = *(float4*)(S + ORST + 4*c4);
        float gg = ln_att_g[f], b2 = ln_att_b[f];
        v.x = (v.x - m4.x)*r4.x*gg + b2;
        v.y = (v.y - m4.y)*r4.y*gg + b2;
        v.z = (v.z - m4.z)*r4.z*gg + b2;
        v.w = (v.w - m4.w)*r4.w*gg + b2;
        X2f4[i4] = v;
    }
    __syncthreads();

    // P3: segment means
    for (int i4 = tid; i4 < 96; i4 += 256){
        int m = i4 >> 2, c4 = i4 & 3;
        float4 a0 = X2f4[(4*m+0)*4 + c4];
        float4 a1 = X2f4[(4*m+1)*4 + c4];
        float4 a2 = X2f4[(4*m+2)*4 + c4];
        float4 a3 = X2f4[(4*m+3)*4 + c4];
        YM4[m*4 + c4] = make_float4(0.25f*(a0.x+a1.x+a2.x+a3.x), 0.25f*(a0.y+a1.y+a2.y+a3.y),
                                    0.25f*(a0.z+a1.z+a2.z+a3.z), 0.25f*(a0.w+a1.w+a2.w+a3.w));
    }
    __syncthreads();

    // P4: k_long/v_long — wave w computes m = 6w..6w+5, lane = d
    {
        int m0 = 6*w;
        float ak[6], av[6];
        #pragma unroll
        for (int j=0;j<6;++j){ ak[j] = bk_r; av[j] = bv_r; }
        #pragma unroll
        for (int c4=0;c4<4;++c4){
            float4 k4 = WK4[c4*64 + lane];
            float4 v4 = WV4[c4*64 + lane];
            #pragma unroll
            for (int j=0;j<6;++j){
                float4 y4 = YM4[(m0+j)*4 + c4];     // broadcast
                ak[j] += dot4(k4, y4);
                av[j] += dot4(v4, y4);
            }
        }
        #pragma unroll
        for (int j=0;j<6;++j){
            S[OKL + (m0+j)*68 + lane] = ak[j];
            S[OVL + (m0+j)*68 + lane] = av[j];
        }
    }
    __syncthreads();

    // P5: attention — wave w owns segments 6w..6w+5; wave-synchronous
    float* wsK = S + OWS + w*WSSTR;
    float* wsQ = wsK + 272;
    float* wsA = wsK + 544;                 // transposed: a[key j][r]
    float4* wsA4 = (float4*)wsA;
    for (int si=0; si<6; ++si){
        int s = 6*w + si;
        // qkv for the 4 rows of this segment (lane = d)
        float aq[4], ak2[4], av2[4];
        #pragma unroll
        for (int r=0;r<4;++r){ aq[r]=bq_r; ak2[r]=bk_r; av2[r]=bv_r; }
        #pragma unroll
        for (int c4=0;c4<4;++c4){
            float4 q4 = WQ4[c4*64 + lane];
            float4 k4 = WK4[c4*64 + lane];
            float4 v4 = WV4[c4*64 + lane];
            #pragma unroll
            for (int r=0;r<4;++r){
                float4 y4 = X2f4[(4*s+r)*4 + c4];    // broadcast
                aq[r] += dot4(q4, y4);
                ak2[r] += dot4(k4, y4);
                av2[r] += dot4(v4, y4);
            }
        }
        #pragma unroll
        for (int r=0;r<4;++r){
            wsQ[r*68 + lane] = aq[r];
            wsK[r*68 + lane] = ak2[r];
        }
        wsync();
        // scores + softmax: lane = (r2 = lane>>4, jj = lane&15); keys jj (4 loc + 12 long) and jj+16
        {
            int r2 = lane >> 4, jj = lane & 15;
            const float* qrow = wsQ + r2*68;
            const float* k1 = (jj < 4) ? (wsK + jj*68) : (S + OKL + (jj-4)*68);
            const float* k2p = S + OKL + (jj+12)*68;   // valid only jj<12 (guarded below)
            float a1 = 0.f, a2 = 0.f;
            #pragma unroll
            for (int dd4=0; dd4<16; ++dd4){
                float4 q4  = *(const float4*)(qrow + 4*dd4);
                float4 k14 = *(const float4*)(k1   + 4*dd4);
                float4 k24 = *(const float4*)(k2p  + 4*dd4);
                a1 += dot4(q4, k14);
                a2 += dot4(q4, k24);
            }
            float s1 = a1*0.125f;
            float s2 = (jj < 12) ? a2*0.125f : -INFINITY;
            float mx = fmaxf(s1, s2);
            #pragma unroll
            for (int off=8; off; off>>=1) mx = fmaxf(mx, __shfl_xor(mx, off, 16));
            float p1 = expf(s1 - mx);
            float p2 = (jj < 12) ? expf(s2 - mx) : 0.f;
            float sm = p1 + p2;
            #pragma unroll
            for (int off=8; off; off>>=1) sm += __shfl_xor(sm, off, 16);
            float inv = 1.f/sm;
            wsA[jj*4 + r2] = p1*inv;
            if (jj < 12) wsA[(16+jj)*4 + r2] = p2*inv;
        }
        wsync();
        // o = a_loc·v_loc + a_long·v_long  (lane = d); overwrite wsK rows with o
        {
            float o0, o1, o2, o3;
            float4 aj = wsA4[0];
            o0 = aj.x*av2[0]; o1 = aj.y*av2[0]; o2 = aj.z*av2[0]; o3 = aj.w*av2[0];
            #pragma unroll
            for (int j=1;j<4;++j){
                aj = wsA4[j];
                o0 += aj.x*av2[j]; o1 += aj.y*av2[j]; o2 += aj.z*av2[j]; o3 += aj.w*av2[j];
            }
            #pragma unroll
            for (int m=0;m<24;++m){
                float vm = S[OVL + m*68 + lane];
                float4 am = wsA4[4+m];              // broadcast
                o0 += am.x*vm; o1 += am.y*vm; o2 += am.z*vm; o3 += am.w*vm;
            }
            wsync();                                 // everyone done reading wsK (scores)
            wsK[0*68 + lane] = o0;
            wsK[1*68 + lane] = o1;
            wsK[2*68 + lane] = o2;
            wsK[3*68 + lane] = o3;
        }
        wsync();
        // out-proj + residual -> x3 written into X2 (rows owned by this wave)
        {
            int r2 = lane >> 4, cc = lane & 15;
            const float* orow = wsK + r2*68;
            float acc = bo_r;
            #pragma unroll
            for (int dd4=0; dd4<16; ++dd4){
                float4 w4 = WO4[dd4*16 + cc];
                float4 o4 = *(const float4*)(orow + 4*dd4);  // broadcast per r-group
                acc += dot4(w4, o4);
            }
            int fc = 4*s + r2;
            float resid = x[xbase + fc*16 + cc] + hs[xbase + fc*16 + cc];
            S[OX2 + fc*16 + cc] = resid + acc;
        }
        wsync();
    }
    __syncthreads();

    // P6: MLP
    ln_stats16(S, tid);
    for (int i4 = tid; i4 < 384; i4 += 256){
        int f = i4 >> 2, c4 = i4 & 3;
        float4 v = X2f4[i4];
        float4 m4 = *(float4*)(S + OMEA + 4*c4);
        float4 r4 = *(float4*)(S + ORST + 4*c4);
        float gg = ln_m_g[f], b2 = ln_m_b[f];
        v.x = (v.x - m4.x)*r4.x*gg + b2;
        v.y = (v.y - m4.y)*r4.y*gg + b2;
        v.z = (v.z - m4.z)*r4.z*gg + b2;
        v.w = (v.w - m4.w)*r4.w*gg + b2;
        ((float4*)(S+OKL))[i4] = v;                   // ynorm in KL region
    }
    __syncthreads();
    for (int i4 = tid; i4 < 384; i4 += 256){
        int f = i4 >> 2, cb = i4 & 3;
        float4 acc = *(const float4*)(bm1 + 4*cb);
        #pragma unroll
        for (int c4=0;c4<4;++c4){
            float4 yn4 = ((float4*)(S+OKL))[f*4 + c4];
            float4 w0 = *(float4*)(S + OWM1 + (4*cb+0)*16 + 4*c4);
            float4 w1 = *(float4*)(S + OWM1 + (4*cb+1)*16 + 4*c4);
            float4 w2 = *(float4*)(S + OWM1 + (4*cb+2)*16 + 4*c4);
            float4 w3 = *(float4*)(S + OWM1 + (4*cb+3)*16 + 4*c4);
            acc.x += dot4(w0, yn4); acc.y += dot4(w1, yn4);
            acc.z += dot4(w2, yn4); acc.w += dot4(w3, yn4);
        }
        acc.x = gelu_erf(acc.x); acc.y = gelu_erf(acc.y);
        acc.z = gelu_erf(acc.z); acc.w = gelu_erf(acc.w);
        ((float4*)(S+OVL))[i4] = acc;                 // y1 in VL region
    }
    __syncthreads();
    for (int i4 = tid; i4 < 384; i4 += 256){
        int f = i4 >> 2, cb = i4 & 3;
        float4 acc = *(const float4*)(bm2 + 4*cb);
        #pragma unroll
        for (int c4=0;c4<4;++c4){
            float4 y14 = ((float4*)(S+OVL))[f*4 + c4];
            float4 w0 = *(float4*)(S + OWM2 + (4*cb+0)*16 + 4*c4);
            float4 w1 = *(float4*)(S + OWM2 + (4*cb+1)*16 + 4*c4);
            float4 w2 = *(float4*)(S + OWM2 + (4*cb+2)*16 + 4*c4);
            float4 w3 = *(float4*)(S + OWM2 + (4*cb+3)*16 + 4*c4);
            acc.x += dot4(w0, y14); acc.y += dot4(w1, y14);
            acc.z += dot4(w2, y14); acc.w += dot4(w3, y14);
        }
        float4 xv = X2f4[i4];
        X2f4[i4] = make_float4(xv.x+acc.x, xv.y+acc.y, xv.z+acc.z, xv.w+acc.w);
    }
    __syncthreads();

    // P7: conv_out + outer residual
    ln_stats16(S, tid);
    if (tid < 192){
        int ch = tid >= 96, f = tid - 96*ch;
        float gg = ln_o_g[f], b2 = ln_o_b[f];
        float acc = b_out[ch];
        #pragma unroll
        for (int c4=0;c4<4;++c4){
            float4 x4 = X2f4[f*4 + c4];
            float4 m4 = *(float4*)(S + OMEA + 4*c4);
            float4 r4 = *(float4*)(S + ORST + 4*c4);
            float4 w4 = *(const float4*)(w_out + ch*16 + 4*c4);
            float4 tm;
            tm.x = (x4.x - m4.x)*r4.x*gg + b2;
            tm.y = (x4.y - m4.y)*r4.y*gg + b2;
            tm.z = (x4.z - m4.z)*r4.z*gg + b2;
            tm.w = (x4.w - m4.w)*r4.w*gg + b2;
            acc += dot4(w4, tm);
        }
        size_t oidx = ((size_t)(b*2+ch)*T_ + t)*F_ + f;
        out[oidx] = input[oidx] + tanhf(acc);
    }
}

extern "C" void kernel_launch(void* const* d_in, const int* in_sizes, int n_in,
                              void* d_out, int out_size, void* d_ws, size_t ws_size,
                              hipStream_t stream)
{
    const float* input   = (const float*)d_in[0];
    const float* ln_in_g = (const float*)d_in[1];
    const float* ln_in_b = (const float*)d_in[2];
    const float* w_in    = (const float*)d_in[3];
    const float* b_in    = (const float*)d_in[4];
    const float* gru_wx  = (const float*)d_in[5];
    const float* gru_wh  = (const float*)d_in[6];
    const float* ln_att_g= (const float*)d_in[7];
    const float* ln_att_b= (const float*)d_in[8];
    const float* wq = (const float*)d_in[9];
    const float* bq = (const float*)d_in[10];
    const float* wk = (const float*)d_in[11];
    const float* bk = (const float*)d_in[12];
    const float* wv = (const float*)d_in[13];
    const float* bv = (const float*)d_in[14];
    const float* wo = (const float*)d_in[15];
    const float* bo = (const float*)d_in[16];
    const float* ln_m_g = (const float*)d_in[17];
    const float* ln_m_b = (const float*)d_in[18];
    const float* w_m1 = (const float*)d_in[19];
    const float* b_m1 = (const float*)d_in[20];
    const float* w_m2 = (const float*)d_in[21];
    const float* b_m2 = (const float*)d_in[22];
    const float* ln_out_g = (const float*)d_in[23];
    const float* ln_out_b = (const float*)d_in[24];
    const float* w_out = (const float*)d_in[25];
    const float* b_out = (const float*)d_in[26];
    float* out = (float*)d_out;

    float* x  = (float*)d_ws;                       // [B,T,F,C]
    float* hs = x + (size_t)B_*T_*F_*C_;            // [B,T,F,C]

    k_conv_in<<<B_*T_, 128, 0, stream>>>(input, ln_in_g, ln_in_b, w_in, b_in, x);
    k_gru<<<192, 128, 0, stream>>>(x, gru_wx, gru_wh, hs, out);
    k_tail<<<B_*T_, 256, 0, stream>>>(x, hs, input, ln_att_g, ln_att_b,
        wq, bq, wk, bk, wv, bv, wo, bo, ln_m_g, ln_m_b, w_m1, b_m1, w_m2, b_m2,
        ln_out_g, ln_out_b, w_out, b_out, out);
}

// Round 8
// 619.445 us; speedup vs baseline: 1.7893x; 1.2550x over previous
//
#include <hip/hip_runtime.h>
#include <math.h>

#define B_ 8
#define T_ 1000
#define F_ 96
#define C_ 16
#define D_ 64
#define EPS_ 1e-5f
#define CH_ 40

typedef short bfrag8 __attribute__((ext_vector_type(8)));
typedef float facc4 __attribute__((ext_vector_type(4)));
#define MFMA16 __builtin_amdgcn_mfma_f32_16x16x32_bf16

__device__ __forceinline__ float gelu_erf(float v){
    return 0.5f*v*(1.0f+erff(v*0.70710678118654752440f));
}
__device__ __forceinline__ float dot4(float4 a, float4 b){
    return a.x*b.x + a.y*b.y + a.z*b.z + a.w*b.w;
}
__device__ __forceinline__ float fast_sigmoid(float a){
    return __builtin_amdgcn_rcpf(1.f + __expf(-a));
}
__device__ __forceinline__ float fast_tanh(float a){
    return 1.f - 2.f*__builtin_amdgcn_rcpf(1.f + __expf(2.f*a));
}
__device__ __forceinline__ unsigned short f2bf(float x){
    unsigned int u = __float_as_uint(x);
    return (unsigned short)((u + 0x7fffu + ((u>>16)&1u)) >> 16);
}
__device__ __forceinline__ float bf2f(unsigned short s){
    return __uint_as_float(((unsigned int)s)<<16);
}
__device__ __forceinline__ unsigned int pack2bf(float a, float b){
    return (unsigned int)f2bf(a) | ((unsigned int)f2bf(b)<<16);
}
__device__ __forceinline__ bfrag8 cvt8(const float* p){
    bfrag8 r;
    #pragma unroll
    for (int j=0;j<8;++j) r[j] = (short)f2bf(p[j]);
    return r;
}

// ---------------- Kernel A: conv_in -> x [B,T,F,C] ----------------
__global__ __launch_bounds__(128) void k_conv_in(
    const float* __restrict__ in, const float* __restrict__ g, const float* __restrict__ bb,
    const float* __restrict__ w_in, const float* __restrict__ b_in,
    float* __restrict__ x)
{
    int bt = blockIdx.x; int b = bt / T_; int t = bt % T_;
    int tid = threadIdx.x;
    __shared__ float r0[128], r1[128], r2[128], r3[128];
    float i0=0.f, i1=0.f;
    size_t base0 = ((size_t)(b*2+0)*T_ + t)*F_;
    size_t base1 = ((size_t)(b*2+1)*T_ + t)*F_;
    if (tid < F_){ i0 = in[base0+tid]; i1 = in[base1+tid]; }
    r0[tid]=i0; r1[tid]=i0*i0; r2[tid]=i1; r3[tid]=i1*i1;
    __syncthreads();
    for (int s=64; s>0; s>>=1){
        if (tid < s){ r0[tid]+=r0[tid+s]; r1[tid]+=r1[tid+s]; r2[tid]+=r2[tid+s]; r3[tid]+=r3[tid+s]; }
        __syncthreads();
    }
    float m0 = r0[0]*(1.f/F_), m1 = r2[0]*(1.f/F_);
    float ri0 = rsqrtf(r1[0]*(1.f/F_) - m0*m0 + EPS_);
    float ri1 = rsqrtf(r3[0]*(1.f/F_) - m1*m1 + EPS_);
    if (tid < F_){
        float gg = g[tid], b0 = bb[tid];
        float y0 = (i0-m0)*ri0*gg + b0;
        float y1 = (i1-m1)*ri1*gg + b0;
        float xv[16];
        #pragma unroll
        for (int c=0;c<C_;++c){
            xv[c] = gelu_erf(w_in[c*2+0]*y0 + w_in[c*2+1]*y1 + b_in[c]);
        }
        float4* xp = (float4*)(x + (((size_t)b*T_+t)*F_ + tid)*C_);
        xp[0] = make_float4(xv[0],xv[1],xv[2],xv[3]);
        xp[1] = make_float4(xv[4],xv[5],xv[6],xv[7]);
        xp[2] = make_float4(xv[8],xv[9],xv[10],xv[11]);
        xp[3] = make_float4(xv[12],xv[13],xv[14],xv[15]);
    }
}

// ---------------- Kernel B: ConvGRU (round-7 producer/consumer + swizzle) ----------------
__global__ __launch_bounds__(128) void k_gru(
    const float* __restrict__ x, const float* __restrict__ wx, const float* __restrict__ wh,
    float* __restrict__ hs, float* __restrict__ d_out)
{
    int blk = blockIdx.x;
    int b = blk / 24, f0 = (blk % 24) * 4;
    int tid = threadIdx.x;
    int wave = tid >> 6, lane = tid & 63;
    int c = lane & 15, ch = lane >> 4;
    int f = f0 + ch;

    __shared__ float GZ[2][CH_*64];
    __shared__ float GR[2][CH_*64];
    __shared__ float GN[2][CH_*64];

    if (wave == 1){
        float4 Wxz[4], Wxr[4], Wxn[4];
        #pragma unroll
        for (int q=0;q<4;++q){
            Wxz[q] = *(const float4*)(wx + ( 0+c)*16 + 4*q);
            Wxr[q] = *(const float4*)(wx + (16+c)*16 + 4*q);
            Wxn[q] = *(const float4*)(wx + (32+c)*16 + 4*q);
        }
        const float* gb0 = x + (size_t)b*T_*(F_*C_) + f*C_;
        #define PRODUCE(K, BF) { \
            _Pragma("unroll 4") \
            for (int tl=0; tl<CH_; ++tl){ \
                const float* xp2 = gb0 + (size_t)((K)*CH_ + tl)*(F_*C_); \
                float4 x0 = *(const float4*)(xp2 + 0); \
                float4 x1 = *(const float4*)(xp2 + 4); \
                float4 x2 = *(const float4*)(xp2 + 8); \
                float4 x3 = *(const float4*)(xp2 + 12); \
                float zx = dot4(Wxz[0],x0)+dot4(Wxz[1],x1)+dot4(Wxz[2],x2)+dot4(Wxz[3],x3); \
                float rx = dot4(Wxr[0],x0)+dot4(Wxr[1],x1)+dot4(Wxr[2],x2)+dot4(Wxr[3],x3); \
                float nx = dot4(Wxn[0],x0)+dot4(Wxn[1],x1)+dot4(Wxn[2],x2)+dot4(Wxn[3],x3); \
                GZ[BF][tl*64+lane]=zx; GR[BF][tl*64+lane]=rx; GN[BF][tl*64+lane]=nx; \
            } }
        PRODUCE(0, 0);
        __syncthreads();
        for (int k=0; k<T_/CH_; ++k){
            if (k+1 < T_/CH_){
                if ((k+1)&1){ PRODUCE(k+1, 1); } else { PRODUCE(k+1, 0); }
            }
            __syncthreads();
        }
        #undef PRODUCE
    } else {
        float Whz[16], Whr[16], Whn[16];
        for (int m=0;m<16;++m){
            int k2 = c ^ m;
            Whz[m] = wh[( 0+c)*16 + k2];
            Whr[m] = wh[(16+c)*16 + k2];
            Whn[m] = wh[(32+c)*16 + k2];
        }
        float hc = 0.f;
        size_t hsb = (size_t)b*T_*(F_*C_) + f0*C_ + lane;
        __syncthreads();
        #define SWZL(m) __int_as_float(__builtin_amdgcn_ds_swizzle(__float_as_int(hc), ((m)<<10)|0x1F))
        for (int k=0; k<T_/CH_; ++k){
            const float* gzp = GZ[k&1];
            const float* grp = GR[k&1];
            const float* gnp = GN[k&1];
            for (int tl=0; tl<CH_; ++tl){
                int idx = tl*64 + lane;
                float gzv = gzp[idx], grv = grp[idx], gnv = gnp[idx];
                float hx0 = hc;
                float hx1 = SWZL(1),  hx2 = SWZL(2),  hx3 = SWZL(3);
                float hx4 = SWZL(4),  hx5 = SWZL(5),  hx6 = SWZL(6),  hx7 = SWZL(7);
                float hx8 = SWZL(8),  hx9 = SWZL(9),  hx10= SWZL(10), hx11= SWZL(11);
                float hx12= SWZL(12), hx13= SWZL(13), hx14= SWZL(14), hx15= SWZL(15);
                float zh = ((Whz[0]*hx0 + Whz[1]*hx1) + (Whz[2]*hx2 + Whz[3]*hx3))
                         + ((Whz[4]*hx4 + Whz[5]*hx5) + (Whz[6]*hx6 + Whz[7]*hx7))
                         + ((Whz[8]*hx8 + Whz[9]*hx9) + (Whz[10]*hx10 + Whz[11]*hx11))
                         + ((Whz[12]*hx12 + Whz[13]*hx13) + (Whz[14]*hx14 + Whz[15]*hx15));
                float rh = ((Whr[0]*hx0 + Whr[1]*hx1) + (Whr[2]*hx2 + Whr[3]*hx3))
                         + ((Whr[4]*hx4 + Whr[5]*hx5) + (Whr[6]*hx6 + Whr[7]*hx7))
                         + ((Whr[8]*hx8 + Whr[9]*hx9) + (Whr[10]*hx10 + Whr[11]*hx11))
                         + ((Whr[12]*hx12 + Whr[13]*hx13) + (Whr[14]*hx14 + Whr[15]*hx15));
                float nh = ((Whn[0]*hx0 + Whn[1]*hx1) + (Whn[2]*hx2 + Whn[3]*hx3))
                         + ((Whn[4]*hx4 + Whn[5]*hx5) + (Whn[6]*hx6 + Whn[7]*hx7))
                         + ((Whn[8]*hx8 + Whn[9]*hx9) + (Whn[10]*hx10 + Whn[11]*hx11))
                         + ((Whn[12]*hx12 + Whn[13]*hx13) + (Whn[14]*hx14 + Whn[15]*hx15));
                float z = fast_sigmoid(gzv + zh);
                float r = fast_sigmoid(grv + rh);
                float n = fast_tanh(gnv + r*nh);
                hc = n + z*(hc - n);
                hs[hsb + (size_t)(k*CH_ + tl)*(F_*C_)] = hc;
            }
            __syncthreads();
        }
        #undef SWZL
        d_out[(size_t)B_*2*T_*F_ + ((size_t)b*C_ + c)*F_ + f] = hc;
    }
}

// ---------------- Kernel C: fused attention + MLP + conv_out (MFMA bf16) ----------------
// LDS map (float offsets; _SH = short offsets = 2x float offset)
#define XR_FL   0        // [96][16] fp32 residual (x+hs), updated in place
#define YB_SH   3072     // [96][24]sh bf16 ynorm / later ynorm2   (fl 1536..2688)
#define YGB_SH  5376     // [96][24]sh bf16 y*G    / later Y1      (fl 2688..3840)
#define PG_SH   3072     // [96][48]sh bf16 long probs (overlays YB+YGB, S5-S6)
#define YMB_SH  7680     // [32][24]sh bf16 segment means          (fl 3840..4224)
#define GTB_SH  8448     // [16][24]sh bf16 G^T (GTB[c2][c1])      (fl 4224..4416)
#define UU_FL   4416
#define VV_FL   4432
#define W0_FL   4448
#define E_FL    4464
#define GL_FL   4560
#define GM_FL   4656
#define MEA_FL  4688
#define RST_FL  4704
#define OSC_FL  4720     // 512: LN scratch; S0-S1: bq (0..64), bk (64..128)
#define VBT_SH  10464    // [64][104]sh bf16 v^T[d][f]             (fl 5232..8560)
#define VLBT_SH 17120    // [64][48]sh bf16 v_long^T[d][m]         (fl 8560..10096)
#define SC_FL   10096    // [96][40] fp32 scores (loc 0..15, long 16..39); pool with:
#define WQS_FL  10096    //   wq staging 1024  (S0-S1)
#define WKS_FL  11120    //   wk staging 1024  (S0-S1)
#define OB_SH   20192    //   [96][72]sh bf16 o[f][d] (S6-S7)      (fl 10096..13552)
#define PL_SH   27872    // [96][48]sh bf16 local probs            (fl 13936..16240)
#define TOTF    16240

__device__ __forceinline__ void ln_stats16(float* S, int tid){
    int c = tid & 15, g = tid >> 4;
    float s=0.f, q=0.f;
    #pragma unroll
    for (int i=0;i<6;++i){
        float v = S[XR_FL + (g*6+i)*16 + c];
        s += v; q += v*v;
    }
    S[OSC_FL + g*16 + c] = s;
    S[OSC_FL + 256 + g*16 + c] = q;
    __syncthreads();
    if (tid < 16){
        float Sm=0.f, Q=0.f;
        #pragma unroll
        for (int g2=0; g2<16; ++g2){
            Sm += S[OSC_FL + g2*16 + tid];
            Q  += S[OSC_FL + 256 + g2*16 + tid];
        }
        float m = Sm*(1.f/96.f);
        S[MEA_FL+tid] = m;
        S[RST_FL+tid] = rsqrtf(Q*(1.f/96.f) - m*m + EPS_);
    }
    __syncthreads();
}

__global__ __launch_bounds__(256) void k_tail(
    const float* __restrict__ x, const float* __restrict__ hs, const float* __restrict__ input,
    const float* __restrict__ ln_att_g, const float* __restrict__ ln_att_b,
    const float* __restrict__ wq, const float* __restrict__ bq,
    const float* __restrict__ wk, const float* __restrict__ bk,
    const float* __restrict__ wv, const float* __restrict__ bv,
    const float* __restrict__ wo, const float* __restrict__ bo,
    const float* __restrict__ ln_m_g, const float* __restrict__ ln_m_b,
    const float* __restrict__ wm1, const float* __restrict__ bm1,
    const float* __restrict__ wm2, const float* __restrict__ bm2,
    const float* __restrict__ ln_o_g, const float* __restrict__ ln_o_b,
    const float* __restrict__ w_out, const float* __restrict__ b_out,
    float* __restrict__ out)
{
    int bt = blockIdx.x; int b = bt / T_; int t = bt % T_;
    int tid = threadIdx.x;
    int w = tid >> 6, lane = tid & 63;
    int n = lane & 15, q2 = lane >> 4;
    __shared__ float S[TOTF];
    short* Ssh = (short*)S;
    const bfrag8 ZF = {0,0,0,0,0,0,0,0};

    size_t xbase = ((size_t)b*T_ + t)*(size_t)(F_*C_);

    // ---- S0: loads ----
    {
        const float4* xg = (const float4*)(x + xbase);
        const float4* hg = (const float4*)(hs + xbase);
        float4* XR4 = (float4*)(S + XR_FL);
        for (int i4 = tid; i4 < 384; i4 += 256){
            float4 a = xg[i4], h = hg[i4];
            XR4[i4] = make_float4(a.x+h.x, a.y+h.y, a.z+h.z, a.w+h.w);
        }
        ((float4*)(S+WQS_FL))[tid] = ((const float4*)wq)[tid];
        ((float4*)(S+WKS_FL))[tid] = ((const float4*)wk)[tid];
        if (tid < 64) S[OSC_FL + tid] = bq[tid];
        else if (tid < 128) S[OSC_FL + tid] = bk[tid-64];
    }
    // per-lane weight frags (global)
    bfrag8 Bv = ZF, Bm1 = ZF, Bm2 = ZF;
    bfrag8 Bo0, Bo1;
    if (q2 < 2){
        Bv  = cvt8(wv  + (16*w + n)*16 + q2*8);
        Bm1 = cvt8(wm1 + n*16 + q2*8);
        Bm2 = cvt8(wm2 + n*16 + q2*8);
    }
    Bo0 = cvt8(wo + n*64 + 0*32 + q2*8);
    Bo1 = cvt8(wo + n*64 + 1*32 + q2*8);
    float bvr  = bv[16*w + n];
    float bor  = bo[n];
    float bm1r = bm1[n];
    float bm2r = bm2[n];
    __syncthreads();

    // ---- S1a: G = s*Wq^T*Wk (bf16, transposed), u' = s*Wq^T*bk, vv' = s*bq*Wk, w0 ----
    {
        int c1 = tid & 15, c2 = tid >> 4;
        float acc = 0.f;
        for (int d=0; d<64; ++d)
            acc += S[WQS_FL + d*16 + c1] * S[WKS_FL + d*16 + c2];
        Ssh[GTB_SH + c2*24 + c1] = (short)f2bf(acc * 0.125f);
        if (tid < 16){
            float a2 = 0.f;
            for (int d=0; d<64; ++d) a2 += S[WQS_FL + d*16 + tid] * S[OSC_FL + 64 + d];
            S[UU_FL + tid] = 0.125f * a2;
        } else if (tid < 32){
            int cc = tid - 16;
            float a2 = 0.f;
            for (int d=0; d<64; ++d) a2 += S[OSC_FL + d] * S[WKS_FL + d*16 + cc];
            S[VV_FL + cc] = 0.125f * a2;
        } else if (tid == 32){
            float a2 = 0.f;
            for (int d=0; d<64; ++d) a2 += S[OSC_FL + d] * S[OSC_FL + 64 + d];
            S[W0_FL] = 0.125f * a2;
        }
    }
    __syncthreads();

    // ---- S1b: attention LN stats ----
    ln_stats16(S, tid);

    // ---- S2: normalize -> YB bf16 [96][24]sh ----
    {
        float4* XR4 = (float4*)(S + XR_FL);
        for (int i4 = tid; i4 < 384; i4 += 256){
            int f = i4 >> 2, c4 = i4 & 3;
            float4 v = XR4[i4];
            float4 m4 = *(float4*)(S + MEA_FL + 4*c4);
            float4 r4 = *(float4*)(S + RST_FL + 4*c4);
            float gg = ln_att_g[f], b2 = ln_att_b[f];
            float y0 = (v.x - m4.x)*r4.x*gg + b2;
            float y1 = (v.y - m4.y)*r4.y*gg + b2;
            float y2 = (v.z - m4.z)*r4.z*gg + b2;
            float y3 = (v.w - m4.w)*r4.w*gg + b2;
            uint2 pk = make_uint2(pack2bf(y0,y1), pack2bf(y2,y3));
            *(uint2*)(Ssh + YB_SH + f*24 + c4*4) = pk;
        }
    }
    __syncthreads();

    // ---- S2b: E/GL, segment means (bf16), zero YMB rows 24..31 ----
    if (tid < 96){
        int f = tid;
        float yv[16];
        uint4 u0 = *(const uint4*)(Ssh + YB_SH + f*24);
        uint4 u1 = *(const uint4*)(Ssh + YB_SH + f*24 + 8);
        unsigned int uu[8] = {u0.x,u0.y,u0.z,u0.w,u1.x,u1.y,u1.z,u1.w};
        #pragma unroll
        for (int j=0;j<8;++j){
            yv[2*j]   = bf2f((unsigned short)(uu[j] & 0xffff));
            yv[2*j+1] = bf2f((unsigned short)(uu[j] >> 16));
        }
        float de = 0.f, dg = 0.f;
        #pragma unroll
        for (int cc=0; cc<16; ++cc){
            de += yv[cc]*S[UU_FL+cc];
            dg += yv[cc]*S[VV_FL+cc];
        }
        S[E_FL + f]  = de + S[W0_FL];
        S[GL_FL + f] = dg;
    }
    for (int e = tid; e < 384; e += 256){
        int m = e >> 4, cc = e & 15;
        float sm = bf2f((unsigned short)Ssh[YB_SH + (4*m+0)*24 + cc])
                 + bf2f((unsigned short)Ssh[YB_SH + (4*m+1)*24 + cc])
                 + bf2f((unsigned short)Ssh[YB_SH + (4*m+2)*24 + cc])
                 + bf2f((unsigned short)Ssh[YB_SH + (4*m+3)*24 + cc]);
        Ssh[YMB_SH + m*24 + cc] = (short)f2bf(0.25f*sm);
    }
    if (tid < 128){
        int row = 24 + (tid >> 4), cc = tid & 15;
        Ssh[YMB_SH + row*24 + cc] = 0;
    }
    __syncthreads();

    // ---- S3: MFMA — v (VBT), v_long (VLBT), YG (YGB); GM ----
    {
        // v: A = YB strip mt, B = Wv^T (Bv), C -> VBT[d][f] b64
        #pragma unroll
        for (int mt=0; mt<6; ++mt){
            bfrag8 A = ZF;
            if (q2 < 2) A = *(const bfrag8*)(Ssh + YB_SH + (mt*16 + n)*24 + q2*8);
            facc4 acc = {bvr, bvr, bvr, bvr};
            acc = MFMA16(A, Bv, acc, 0, 0, 0);
            uint2 pk = make_uint2(pack2bf(acc[0],acc[1]), pack2bf(acc[2],acc[3]));
            *(uint2*)(Ssh + VBT_SH + (16*w + n)*104 + mt*16 + q2*4) = pk;
        }
        // v_long: A = YMB tiles, B = Bv, C -> VLBT[d][m] b64
        #pragma unroll
        for (int mt=0; mt<2; ++mt){
            bfrag8 A = ZF;
            if (q2 < 2) A = *(const bfrag8*)(Ssh + YMB_SH + (mt*16 + n)*24 + q2*8);
            facc4 acc = {bvr, bvr, bvr, bvr};
            acc = MFMA16(A, Bv, acc, 0, 0, 0);
            uint2 pk = make_uint2(pack2bf(acc[0],acc[1]), pack2bf(acc[2],acc[3]));
            *(uint2*)(Ssh + VLBT_SH + (16*w + n)*48 + mt*16 + q2*4) = pk;
        }
        // YG = y*G: A = YB strip, B = GTB; C scattered b16 -> YGB[f][c2]
        bfrag8 Bg = ZF;
        if (q2 < 2) Bg = *(const bfrag8*)(Ssh + GTB_SH + n*24 + q2*8);
        for (int mt = w; mt < 6; mt += 4){
            bfrag8 A = ZF;
            if (q2 < 2) A = *(const bfrag8*)(Ssh + YB_SH + (mt*16 + n)*24 + q2*8);
            facc4 acc = {0.f,0.f,0.f,0.f};
            acc = MFMA16(A, Bg, acc, 0, 0, 0);
            #pragma unroll
            for (int r=0;r<4;++r)
                Ssh[YGB_SH + (mt*16 + q2*4 + r)*24 + n] = (short)f2bf(acc[r]);
        }
        // GM[m] = ym[m] . vv'
        if (tid >= 224 && tid < 248){
            int m = tid - 224;
            float a2 = 0.f;
            #pragma unroll
            for (int cc=0; cc<16; ++cc)
                a2 += bf2f((unsigned short)Ssh[YMB_SH + m*24 + cc]) * S[VV_FL + cc];
            S[GM_FL + m] = a2;
        }
    }
    __syncthreads();

    // ---- S4: scores (18 tiles: per strip 1 local + 2 long) ----
    for (int j = w; j < 18; j += 4){
        int mt = j / 3, kind = j % 3;
        bfrag8 A = ZF;
        if (q2 < 2) A = *(const bfrag8*)(Ssh + YGB_SH + (mt*16 + n)*24 + q2*8);
        bfrag8 Bf = ZF;
        if (kind == 0){
            if (q2 < 2) Bf = *(const bfrag8*)(Ssh + YB_SH + (mt*16 + n)*24 + q2*8);
        } else {
            int nt = kind - 1;
            if (q2 < 2) Bf = *(const bfrag8*)(Ssh + YMB_SH + (nt*16 + n)*24 + q2*8);
        }
        facc4 acc = {0.f,0.f,0.f,0.f};
        acc = MFMA16(A, Bf, acc, 0, 0, 0);
        if (kind == 0){
            #pragma unroll
            for (int r=0;r<4;++r)
                S[SC_FL + (mt*16 + q2*4 + r)*40 + n] = acc[r];
        } else {
            int nt = kind - 1;
            if (!(nt == 1 && n >= 8)){
                #pragma unroll
                for (int r=0;r<4;++r)
                    S[SC_FL + (mt*16 + q2*4 + r)*40 + 16 + nt*16 + n] = acc[r];
            }
        }
    }
    __syncthreads();

    // ---- S5: softmax (threads 0..95, one row each) ----
    if (tid < 96){
        int f = tid;
        int lsq = (f >> 2) & 3;
        float e_ = S[E_FL + f];
        const float* row = S + SC_FL + f*40;
        float sl[4];
        #pragma unroll
        for (int j=0;j<4;++j)
            sl[j] = row[4*lsq + j] + e_ + S[GL_FL + (f & ~3) + j];
        float sg[24];
        #pragma unroll
        for (int m=0;m<24;++m)
            sg[m] = row[16 + m] + e_ + S[GM_FL + m];
        float mx = sl[0];
        #pragma unroll
        for (int j=1;j<4;++j) mx = fmaxf(mx, sl[j]);
        #pragma unroll
        for (int m=0;m<24;++m) mx = fmaxf(mx, sg[m]);
        float sum = 0.f;
        #pragma unroll
        for (int j=0;j<4;++j){ sl[j] = __expf(sl[j]-mx); sum += sl[j]; }
        #pragma unroll
        for (int m=0;m<24;++m){ sg[m] = __expf(sg[m]-mx); sum += sg[m]; }
        float inv = __builtin_amdgcn_rcpf(sum);
        // PL row: 32 bf16, valid 4 at cols 4*lsq
        unsigned int lo = pack2bf(sl[0]*inv, sl[1]*inv);
        unsigned int hi = pack2bf(sl[2]*inv, sl[3]*inv);
        uint4 z4 = make_uint4(0u,0u,0u,0u);
        uint4 p0 = make_uint4(lsq==0?lo:0u, lsq==0?hi:0u, lsq==1?lo:0u, lsq==1?hi:0u);
        uint4 p1 = make_uint4(lsq==2?lo:0u, lsq==2?hi:0u, lsq==3?lo:0u, lsq==3?hi:0u);
        uint4* plp = (uint4*)(Ssh + PL_SH + f*48);
        plp[0] = p0; plp[1] = p1; plp[2] = z4; plp[3] = z4;
        // PG row: 24 bf16 + 8 zeros
        unsigned int gdw[12];
        #pragma unroll
        for (int m=0;m<12;++m) gdw[m] = pack2bf(sg[2*m]*inv, sg[2*m+1]*inv);
        uint4* pgp = (uint4*)(Ssh + PG_SH + f*48);
        pgp[0] = make_uint4(gdw[0],gdw[1],gdw[2],gdw[3]);
        pgp[1] = make_uint4(gdw[4],gdw[5],gdw[6],gdw[7]);
        pgp[2] = make_uint4(gdw[8],gdw[9],gdw[10],gdw[11]);
        pgp[3] = z4;
    }
    __syncthreads();

    // ---- S6: o^T = v^T*P_loc^T + v_long^T*P_long^T -> OB[f][d] ----
    {
        bfrag8 Avl = *(const bfrag8*)(Ssh + VLBT_SH + (16*w + n)*48 + q2*8);
        #pragma unroll
        for (int nt=0; nt<6; ++nt){
            bfrag8 Avb = ZF;
            if (q2 < 2) Avb = *(const bfrag8*)(Ssh + VBT_SH + (16*w + n)*104 + nt*16 + q2*8);
            bfrag8 Bpl = *(const bfrag8*)(Ssh + PL_SH + (nt*16 + n)*48 + q2*8);
            bfrag8 Bpg = *(const bfrag8*)(Ssh + PG_SH + (nt*16 + n)*48 + q2*8);
            facc4 acc = {0.f,0.f,0.f,0.f};
            acc = MFMA16(Avb, Bpl, acc, 0, 0, 0);
            acc = MFMA16(Avl, Bpg, acc, 0, 0, 0);
            uint2 pk = make_uint2(pack2bf(acc[0],acc[1]), pack2bf(acc[2],acc[3]));
            *(uint2*)(Ssh + OB_SH + (nt*16 + n)*72 + 16*w + q2*4) = pk;
        }
    }
    __syncthreads();

    // ---- S7: out-proj + residual into XR ----
    for (int mt = w; mt < 6; mt += 4){
        bfrag8 A0 = *(const bfrag8*)(Ssh + OB_SH + (mt*16 + n)*72 + 0*32 + q2*8);
        bfrag8 A1 = *(const bfrag8*)(Ssh + OB_SH + (mt*16 + n)*72 + 1*32 + q2*8);
        facc4 acc = {bor, bor, bor, bor};
        acc = MFMA16(A0, Bo0, acc, 0, 0, 0);
        acc = MFMA16(A1, Bo1, acc, 0, 0, 0);
        #pragma unroll
        for (int r=0;r<4;++r)
            S[XR_FL + (mt*16 + q2*4 + r)*16 + n] += acc[r];
    }
    __syncthreads();

    // ---- S8: MLP ----
    ln_stats16(S, tid);
    {
        float4* XR4 = (float4*)(S + XR_FL);
        for (int i4 = tid; i4 < 384; i4 += 256){
            int f = i4 >> 2, c4 = i4 & 3;
            float4 v = XR4[i4];
            float4 m4 = *(float4*)(S + MEA_FL + 4*c4);
            float4 r4 = *(float4*)(S + RST_FL + 4*c4);
            float gg = ln_m_g[f], b2 = ln_m_b[f];
            float y0 = (v.x - m4.x)*r4.x*gg + b2;
            float y1 = (v.y - m4.y)*r4.y*gg + b2;
            float y2 = (v.z - m4.z)*r4.z*gg + b2;
            float y3 = (v.w - m4.w)*r4.w*gg + b2;
            uint2 pk = make_uint2(pack2bf(y0,y1), pack2bf(y2,y3));
            *(uint2*)(Ssh + YB_SH + f*24 + c4*4) = pk;
        }
    }
    __syncthreads();
    for (int mt = w; mt < 6; mt += 4){
        bfrag8 A = ZF;
        if (q2 < 2) A = *(const bfrag8*)(Ssh + YB_SH + (mt*16 + n)*24 + q2*8);
        facc4 acc = {bm1r, bm1r, bm1r, bm1r};
        acc = MFMA16(A, Bm1, acc, 0, 0, 0);
        #pragma unroll
        for (int r=0;r<4;++r)
            Ssh[YGB_SH + (mt*16 + q2*4 + r)*24 + n] = (short)f2bf(gelu_erf(acc[r]));
    }
    __syncthreads();
    for (int mt = w; mt < 6; mt += 4){
        bfrag8 A = ZF;
        if (q2 < 2) A = *(const bfrag8*)(Ssh + YGB_SH + (mt*16 + n)*24 + q2*8);
        facc4 acc = {bm2r, bm2r, bm2r, bm2r};
        acc = MFMA16(A, Bm2, acc, 0, 0, 0);
        #pragma unroll
        for (int r=0;r<4;++r)
            S[XR_FL + (mt*16 + q2*4 + r)*16 + n] += acc[r];
    }
    __syncthreads();

    // ---- S9: conv_out + outer residual ----
    ln_stats16(S, tid);
    if (tid < 192){
        int ch = tid >= 96, f = tid - 96*ch;
        float gg = ln_o_g[f], b2 = ln_o_b[f];
        float acc = b_out[ch];
        float4* XR4 = (float4*)(S + XR_FL);
        #pragma unroll
        for (int c4=0;c4<4;++c4){
            float4 x4 = XR4[f*4 + c4];
            float4 m4 = *(float4*)(S + MEA_FL + 4*c4);
            float4 r4 = *(float4*)(S + RST_FL + 4*c4);
            float4 w4 = *(const float4*)(w_out + ch*16 + 4*c4);
            float4 tm;
            tm.x = (x4.x - m4.x)*r4.x*gg + b2;
            tm.y = (x4.y - m4.y)*r4.y*gg + b2;
            tm.z = (x4.z - m4.z)*r4.z*gg + b2;
            tm.w = (x4.w - m4.w)*r4.w*gg + b2;
            acc += dot4(w4, tm);
        }
        size_t oidx = ((size_t)(b*2+ch)*T_ + t)*F_ + f;
        out[oidx] = input[oidx] + tanhf(acc);
    }
}

extern "C" void kernel_launch(void* const* d_in, const int* in_sizes, int n_in,
                              void* d_out, int out_size, void* d_ws, size_t ws_size,
                              hipStream_t stream)
{
    const float* input   = (const float*)d_in[0];
    const float* ln_in_g = (const float*)d_in[1];
    const float* ln_in_b = (const float*)d_in[2];
    const float* w_in    = (const float*)d_in[3];
    const float* b_in    = (const float*)d_in[4];
    const float* gru_wx  = (const float*)d_in[5];
    const float* gru_wh  = (const float*)d_in[6];
    const float* ln_att_g= (const float*)d_in[7];
    const float* ln_att_b= (const float*)d_in[8];
    const float* wq = (const float*)d_in[9];
    const float* bq = (const float*)d_in[10];
    const float* wk = (const float*)d_in[11];
    const float* bk = (const float*)d_in[12];
    const float* wv = (const float*)d_in[13];
    const float* bv = (const float*)d_in[14];
    const float* wo = (const float*)d_in[15];
    const float* bo = (const float*)d_in[16];
    const float* ln_m_g = (const float*)d_in[17];
    const float* ln_m_b = (const float*)d_in[18];
    const float* w_m1 = (const float*)d_in[19];
    const float* b_m1 = (const float*)d_in[20];
    const float* w_m2 = (const float*)d_in[21];
    const float* b_m2 = (const float*)d_in[22];
    const float* ln_out_g = (const float*)d_in[23];
    const float* ln_out_b = (const float*)d_in[24];
    const float* w_out = (const float*)d_in[25];
    const float* b_out = (const float*)d_in[26];
    float* out = (float*)d_out;

    float* x  = (float*)d_ws;                       // [B,T,F,C]
    float* hs = x + (size_t)B_*T_*F_*C_;            // [B,T,F,C]

    k_conv_in<<<B_*T_, 128, 0, stream>>>(input, ln_in_g, ln_in_b, w_in, b_in, x);
    k_gru<<<192, 128, 0, stream>>>(x, gru_wx, gru_wh, hs, out);
    k_tail<<<B_*T_, 256, 0, stream>>>(x, hs, input, ln_att_g, ln_att_b,
        wq, bq, wk, bk, wv, bv, wo, bo, ln_m_g, ln_m_b, w_m1, b_m1, w_m2, b_m2,
        ln_out_g, ln_out_b, w_out, b_out, out);
}